// Round 1
// baseline (2762.167 us; speedup 1.0000x reference)
//
#include <hip/hip_runtime.h>

#define NN 100000
#define NE 1600000
#define TT 8
#define KPAD 160   // 148 padded to 160 (BK=40 x 4 tiles)

__device__ __forceinline__ float sigf(float x) { return 1.f / (1.f + __expf(-x)); }
__device__ __forceinline__ float tanhf_(float x) { return 1.f - 2.f / (__expf(2.f * x) + 1.f); }

// ---------------- edge dtype detect: int64 => odd int32 words are all 0 ----------------
__global__ void k_detect(const int* __restrict__ ei, int* flag) {
    int i = blockIdx.x * 256 + threadIdx.x;   // sample first 4096 pairs (safe either way)
    if (ei[2 * i + 1] != 0) atomicOr(flag, 1);  // nonzero odd word => really int32 layout
}

// ---------------- CSR build ----------------
__global__ void k_hist(const int* __restrict__ ei, const int* __restrict__ flag, int* cnt) {
    int e = blockIdx.x * 256 + threadIdx.x;
    if (e >= NE) return;
    int is32 = *flag;
    int d = is32 ? ei[NE + e] : ei[2 * (NE + e)];
    atomicAdd(&cnt[d], 1);
}

__global__ void k_scanblk(const int* __restrict__ cnt, int* off, int* bsum) {
    __shared__ int tmp[1024];
    int i = blockIdx.x * 1024 + threadIdx.x;
    int v = (i < NN) ? cnt[i] : 0;
    tmp[threadIdx.x] = v;
    __syncthreads();
    for (int d = 1; d < 1024; d <<= 1) {
        int t = (threadIdx.x >= d) ? tmp[threadIdx.x - d] : 0;
        __syncthreads();
        tmp[threadIdx.x] += t;
        __syncthreads();
    }
    if (i < NN) off[i + 1] = tmp[threadIdx.x];
    if (threadIdx.x == 1023) bsum[blockIdx.x] = tmp[1023];
}

__global__ void k_scantop(int* bsum, int nb) {
    if (threadIdx.x == 0) {
        int run = 0;
        for (int b = 0; b < nb; b++) { int t = bsum[b]; bsum[b] = run; run += t; }
    }
}

__global__ void k_scanadd(int* off, const int* __restrict__ bsum) {
    int i = blockIdx.x * 1024 + threadIdx.x;
    if (i < NN) off[i + 1] += bsum[blockIdx.x];
    if (i == 0) off[0] = 0;
}

__global__ void k_scatter(const int* __restrict__ ei, const int* __restrict__ flag,
                          int* cursor, int* csr) {
    int e = blockIdx.x * 256 + threadIdx.x;
    if (e >= NE) return;
    int is32 = *flag;
    int s = is32 ? ei[e] : ei[2 * e];
    int d = is32 ? ei[NE + e] : ei[2 * (NE + e)];
    int pos = atomicAdd(&cursor[d], 1);
    csr[pos] = s;
}

// ---------------- fold weights: Wbig (stored transposed [KPAD][256]) ----------------
__global__ void k_prep(const float* __restrict__ W_ih, const float* __restrict__ W_hh,
                       const float* __restrict__ b_ih, const float* __restrict__ b_hh,
                       const float* __restrict__ W_rel, const float* __restrict__ b_rel,
                       const float* __restrict__ W_root, float* WgT, float* bg) {
    int j = threadIdx.x;          // 0..255 gate-output
    int k = blockIdx.x;           // 0..159 => WgT row; 160 => bias
    if (k < KPAD) {
        float v = 0.f;
        if (k < 20) {
            v = W_ih[j * 84 + k];
        } else if (k < 84) {
            int kk = k - 20;
            float a = 0.f;
            for (int m = 0; m < 64; m++) a += W_ih[j * 84 + 20 + m] * W_rel[m * 64 + kk];
            v = a;
        } else if (k < 148) {
            int kk = k - 84;
            float a = W_hh[j * 64 + kk];
            for (int m = 0; m < 64; m++) a += W_ih[j * 84 + 20 + m] * W_root[m * 64 + kk];
            v = a;
        }
        WgT[k * 256 + j] = v;
    } else {
        float a = b_ih[j] + b_hh[j];
        for (int m = 0; m < 64; m++) a += W_ih[j * 84 + 20 + m] * b_rel[m];
        bg[j] = a;
    }
}

// ---------------- segment sum: wave per dst node, lane = feature ----------------
__global__ __launch_bounds__(256) void k_gather(const int* __restrict__ off,
                                                const int* __restrict__ csr,
                                                const float* __restrict__ h,
                                                float* __restrict__ agg) {
    int w = ((blockIdx.x * 256 + threadIdx.x) >> 6);
    int lane = threadIdx.x & 63;
    if (w >= NN) return;
    int e0 = off[w], e1 = off[w + 1];
    float acc = 0.f, acc2 = 0.f;
    int e = e0;
    for (; e + 2 <= e1; e += 2) {
        int s0 = csr[e], s1 = csr[e + 1];
        acc += h[(size_t)s0 * 64 + lane];
        acc2 += h[(size_t)s1 * 64 + lane];
    }
    if (e < e1) acc += h[(size_t)csr[e] * 64 + lane];
    agg[(size_t)w * 64 + lane] = acc + acc2;
}

// ---------------- gnn_out (only needed at t = T-1) ----------------
__global__ void k_gnn(const float* __restrict__ agg, const float* __restrict__ h,
                      const float* __restrict__ W_rel, const float* __restrict__ b_rel,
                      const float* __restrict__ W_root, float* gnn) {
    int g = blockIdx.x * 256 + threadIdx.x;
    if (g >= NN * 64) return;
    int n = g >> 6, j = g & 63;
    float a = b_rel[j];
    const float* ar = agg + (size_t)n * 64;
    const float* hr = h + (size_t)n * 64;
    for (int k = 0; k < 64; k++)
        a += ar[k] * W_rel[j * 64 + k] + hr[k] * W_root[j * 64 + k];
    gnn[g] = a;
}

// ---------------- fused gates GEMM + LSTM cell update ----------------
// tile: 64 nodes x 256 gates, K=160 (BK=40 x 4). thread = (ng=tid>>4: 4-node group, jb=tid&15: 4 j's x 4 gates)
__global__ __launch_bounds__(256) void k_gates(const float* __restrict__ x,
                                               const float* __restrict__ agg,
                                               float* __restrict__ h, float* __restrict__ c,
                                               const float* __restrict__ WgT,
                                               const float* __restrict__ bg, int t) {
    __shared__ __align__(16) float Zs[64 * 44];     // node-major, stride 44 (pad)
    __shared__ __align__(16) float Ws[40 * 256];    // k-major
    const int tid = threadIdx.x;
    const int nblk = blockIdx.x * 64;
    const int ng = tid >> 4;
    const int jb4 = (tid & 15) * 4;

    float acc[4][4][4];   // [gate][q][node]
#pragma unroll
    for (int g = 0; g < 4; g++)
#pragma unroll
        for (int q = 0; q < 4; q++)
#pragma unroll
            for (int r = 0; r < 4; r++) acc[g][q][r] = 0.f;

    for (int kt = 0; kt < 4; ++kt) {
        __syncthreads();
        // stage W tile (40x256)
#pragma unroll
        for (int s = 0; s < 10; ++s) {
            int f4 = tid + 256 * s;
            int k = f4 >> 6, jq = f4 & 63;
            float4 w = *(const float4*)(WgT + (size_t)(kt * 40 + k) * 256 + jq * 4);
            *(float4*)(Ws + k * 256 + jq * 4) = w;
        }
        // stage Z tile (64 nodes x 40 k) from x / agg / h
        for (int s = 0; s < 3; ++s) {
            int slot = tid + 256 * s;
            if (slot < 640) {
                int n = slot / 10, kq = slot - n * 10;
                int n_g = nblk + n;
                int kk4 = kt * 40 + kq * 4;
                float4 z = make_float4(0.f, 0.f, 0.f, 0.f);
                if (n_g < NN) {
                    if (kk4 < 20) {
                        const float* xp = x + (size_t)n_g * 240 + (10 + kk4) * 8 + t;
                        z.x = xp[0]; z.y = xp[8]; z.z = xp[16]; z.w = xp[24];
                    } else if (kk4 < 84) {
                        z = *(const float4*)(agg + (size_t)n_g * 64 + (kk4 - 20));
                    } else if (kk4 < 148) {
                        z = *(const float4*)(h + (size_t)n_g * 64 + (kk4 - 84));
                    }
                }
                *(float4*)(Zs + n * 44 + kq * 4) = z;
            }
        }
        __syncthreads();
#pragma unroll 4
        for (int k = 0; k < 40; ++k) {
            float zr[4];
#pragma unroll
            for (int r = 0; r < 4; r++) zr[r] = Zs[(ng * 4 + r) * 44 + k];
#pragma unroll
            for (int g = 0; g < 4; ++g) {
                float4 w = *(const float4*)(Ws + k * 256 + g * 64 + jb4);
#pragma unroll
                for (int r = 0; r < 4; r++) {
                    acc[g][0][r] += zr[r] * w.x;
                    acc[g][1][r] += zr[r] * w.y;
                    acc[g][2][r] += zr[r] * w.z;
                    acc[g][3][r] += zr[r] * w.w;
                }
            }
        }
    }
    // LSTM epilogue — thread owns full i,f,g,o for its (node, j) pairs
#pragma unroll
    for (int r = 0; r < 4; ++r) {
        int n_g = nblk + ng * 4 + r;
        if (n_g >= NN) continue;
        float4 cold = *(const float4*)(c + (size_t)n_g * 64 + jb4);
        float co[4] = {cold.x, cold.y, cold.z, cold.w};
        float cn[4], hn[4];
#pragma unroll
        for (int q = 0; q < 4; ++q) {
            int j = jb4 + q;
            float iv = sigf(acc[0][q][r] + bg[j]);
            float fv = sigf(acc[1][q][r] + bg[64 + j]);
            float gv = tanhf_(acc[2][q][r] + bg[128 + j]);
            float ov = sigf(acc[3][q][r] + bg[192 + j]);
            cn[q] = fv * co[q] + iv * gv;
            hn[q] = ov * tanhf_(cn[q]);
        }
        *(float4*)(c + (size_t)n_g * 64 + jb4) = make_float4(cn[0], cn[1], cn[2], cn[3]);
        *(float4*)(h + (size_t)n_g * 64 + jb4) = make_float4(hn[0], hn[1], hn[2], hn[3]);
    }
}

// ---------------- batch-norm stats over N per feature ----------------
__global__ void k_stats(const float* __restrict__ h, const float* __restrict__ gnn,
                        float* sums, float* sumsq) {
    int f = threadIdx.x;                       // 0..127 (block = 128)
    const float* base = (f < 64) ? h : gnn;
    int ff = f & 63;
    float s = 0.f, s2 = 0.f;
    for (int n = blockIdx.x; n < NN; n += gridDim.x) {
        float v = base[(size_t)n * 64 + ff];
        s += v; s2 += v * v;
    }
    atomicAdd(&sums[f], s);
    atomicAdd(&sumsq[f], s2);
}

__global__ void k_normprep(const float* __restrict__ sums, const float* __restrict__ sumsq,
                           const float* __restrict__ gamma, const float* __restrict__ beta,
                           float* ab) {
    int f = threadIdx.x;   // 128
    float mean = sums[f] / (float)NN;
    float var = sumsq[f] / (float)NN - mean * mean;
    float a = gamma[f] * rsqrtf(var + 1e-5f);
    ab[f] = a;
    ab[128 + f] = beta[f] - mean * a;
}

// ---------------- h1 = relu(normed @ W1.T + b1), wave per node ----------------
__global__ __launch_bounds__(256) void k_h1(const float* __restrict__ h,
                                            const float* __restrict__ gnn,
                                            const float* __restrict__ ab,
                                            const float* __restrict__ W1,
                                            const float* __restrict__ b1, float* h1) {
    __shared__ float W1T[128 * 66];
    __shared__ float fr[4][128];
    int tid = threadIdx.x, w = tid >> 6, lane = tid & 63;
    for (int idx = tid; idx < 64 * 128; idx += 256) {
        int j = idx >> 7, k = idx & 127;
        W1T[k * 66 + j] = W1[idx];
    }
    __syncthreads();
    float bb = b1[lane];
    for (int n = blockIdx.x * 4 + w; n < NN; n += gridDim.x * 4) {
        float v0 = h[(size_t)n * 64 + lane] * ab[lane] + ab[128 + lane];
        float v1 = gnn[(size_t)n * 64 + lane] * ab[64 + lane] + ab[192 + lane];
        fr[w][lane] = v0;
        fr[w][64 + lane] = v1;
        __threadfence_block();
        float a = bb;
#pragma unroll 8
        for (int k = 0; k < 128; k++) a += fr[w][k] * W1T[k * 66 + lane];
        h1[(size_t)n * 64 + lane] = fmaxf(a, 0.f);
        __threadfence_block();
    }
}

// ---------------- out = sigmoid(relu(h1@W2.T+b2) @ W_out.T + b_out) ----------------
__global__ __launch_bounds__(256) void k_out(const float* __restrict__ h1,
                                             const float* __restrict__ W2,
                                             const float* __restrict__ b2,
                                             const float* __restrict__ W_out,
                                             const float* __restrict__ b_out,
                                             float* __restrict__ out) {
    __shared__ float W2T[64 * 130];
    __shared__ float hb[4][64];
    int tid = threadIdx.x, w = tid >> 6, lane = tid & 63;
    for (int idx = tid; idx < 128 * 64; idx += 256) {
        int jj = idx >> 6, k = idx & 63;
        W2T[k * 130 + jj] = W2[idx];
    }
    __syncthreads();
    float wo0 = W_out[lane], wo1 = W_out[64 + lane];
    float bb0 = b2[lane], bb1 = b2[64 + lane], bo = b_out[0];
    for (int n = blockIdx.x * 4 + w; n < NN; n += gridDim.x * 4) {
        hb[w][lane] = h1[(size_t)n * 64 + lane];
        __threadfence_block();
        float a0 = bb0, a1 = bb1;
#pragma unroll 8
        for (int k = 0; k < 64; k++) {
            float hv = hb[w][k];
            a0 += hv * W2T[k * 130 + lane];
            a1 += hv * W2T[k * 130 + 64 + lane];
        }
        float p = fmaxf(a0, 0.f) * wo0 + fmaxf(a1, 0.f) * wo1;
        for (int o2 = 32; o2; o2 >>= 1) p += __shfl_down(p, o2, 64);
        if (lane == 0) out[n] = sigf(p + bo);
        __threadfence_block();
    }
}

extern "C" void kernel_launch(void* const* d_in, const int* in_sizes, int n_in,
                              void* d_out, int out_size, void* d_ws, size_t ws_size,
                              hipStream_t stream) {
    const float* x      = (const float*)d_in[0];
    const int*   ei     = (const int*)d_in[1];
    const float* W_ih   = (const float*)d_in[4];
    const float* W_hh   = (const float*)d_in[5];
    const float* b_ih   = (const float*)d_in[6];
    const float* b_hh   = (const float*)d_in[7];
    const float* W_rel  = (const float*)d_in[8];
    const float* b_rel  = (const float*)d_in[9];
    const float* W_root = (const float*)d_in[10];
    const float* gamma  = (const float*)d_in[11];
    const float* beta   = (const float*)d_in[12];
    const float* W1     = (const float*)d_in[13];
    const float* b1     = (const float*)d_in[14];
    const float* W2     = (const float*)d_in[15];
    const float* b2     = (const float*)d_in[16];
    const float* W_out  = (const float*)d_in[17];
    const float* b_out  = (const float*)d_in[18];
    float* out = (float*)d_out;

    char* ws = (char*)d_ws;
    size_t o = 0;
    auto carve = [&](size_t bytes) { char* p = ws + o; o += (bytes + 255) & ~(size_t)255; return p; };
    int*   off    = (int*)carve((NN + 1) * 4);
    int*   cnt    = (int*)carve(NN * 4);          // reused as cursor
    int*   bsum   = (int*)carve(128 * 4);
    int*   flag   = (int*)carve(256);
    int*   csr    = (int*)carve((size_t)NE * 4);
    float* h      = (float*)carve((size_t)NN * 64 * 4);
    float* c      = (float*)carve((size_t)NN * 64 * 4);
    float* agg    = (float*)carve((size_t)NN * 64 * 4);   // later reused as h1
    float* gnn    = (float*)carve((size_t)NN * 64 * 4);
    float* WgT    = (float*)carve((size_t)KPAD * 256 * 4);
    float* bg     = (float*)carve(256 * 4);
    float* sums   = (float*)carve(128 * 4);
    float* sumsq  = (float*)carve(128 * 4);
    float* ab     = (float*)carve(256 * 4);
    float* h1     = agg;

    const int nscan = (NN + 1023) / 1024;   // 98

    // edge dtype detect + CSR build
    hipMemsetAsync(flag, 0, 4, stream);
    hipMemsetAsync(cnt, 0, NN * 4, stream);
    k_detect<<<16, 256, 0, stream>>>(ei, flag);
    k_hist<<<(NE + 255) / 256, 256, 0, stream>>>(ei, flag, cnt);
    k_scanblk<<<nscan, 1024, 0, stream>>>(cnt, off, bsum);
    k_scantop<<<1, 64, 0, stream>>>(bsum, nscan);
    k_scanadd<<<nscan, 1024, 0, stream>>>(off, bsum);
    hipMemcpyAsync(cnt, off, NN * 4, hipMemcpyDeviceToDevice, stream);  // cursor = off
    k_scatter<<<(NE + 255) / 256, 256, 0, stream>>>(ei, flag, cnt, csr);

    // init state + folded weights
    hipMemsetAsync(h, 0, (size_t)NN * 64 * 4 * 2, stream);   // h and c (contiguous)
    k_prep<<<KPAD + 1, 256, 0, stream>>>(W_ih, W_hh, b_ih, b_hh, W_rel, b_rel, W_root, WgT, bg);

    // 8 recurrent steps
    for (int t = 0; t < TT; ++t) {
        if (t == 0)
            hipMemsetAsync(agg, 0, (size_t)NN * 64 * 4, stream);   // h==0 => agg==0
        else
            k_gather<<<(NN + 3) / 4, 256, 0, stream>>>(off, csr, h, agg);
        if (t == TT - 1)
            k_gnn<<<(NN * 64 + 255) / 256, 256, 0, stream>>>(agg, h, W_rel, b_rel, W_root, gnn);
        k_gates<<<(NN + 63) / 64, 256, 0, stream>>>(x, agg, h, c, WgT, bg, t);
    }

    // batch-norm stats + head
    hipMemsetAsync(sums, 0, 256 * 4 + 256, stream);   // sums+sumsq (+ab slack not needed but safe)
    k_stats<<<1024, 128, 0, stream>>>(h, gnn, sums, sumsq);
    k_normprep<<<1, 128, 0, stream>>>(sums, sumsq, gamma, beta, ab);
    k_h1<<<1024, 256, 0, stream>>>(h, gnn, ab, W1, b1, h1);
    k_out<<<1024, 256, 0, stream>>>(h1, W2, b2, W_out, b_out, out);
}

// Round 2
// 2445.355 us; speedup vs baseline: 1.1296x; 1.1296x over previous
//
#include <hip/hip_runtime.h>

#define NN 100000
#define NE 1600000
#define TT 8
#define KPAD 160     // 148 padded to 160 (BK=40 x 4 tiles)
#define JWFULL 320   // 256 gate outputs + 64 gnn outputs (folded weight width)

__device__ __forceinline__ float sigf(float x) { return 1.f / (1.f + __expf(-x)); }
__device__ __forceinline__ float tanhf_(float x) { return 1.f - 2.f / (__expf(2.f * x) + 1.f); }

// ---------------- edge dtype detect: int64 => odd int32 words are all 0 ----------------
__global__ void k_detect(const int* __restrict__ ei, int* flag) {
    int i = blockIdx.x * 256 + threadIdx.x;
    if (ei[2 * i + 1] != 0) atomicOr(flag, 1);
}

// ---------------- CSR build ----------------
__global__ void k_hist(const int* __restrict__ ei, const int* __restrict__ flag, int* cnt) {
    int e = blockIdx.x * 256 + threadIdx.x;
    if (e >= NE) return;
    int is32 = *flag;
    int d = is32 ? ei[NE + e] : ei[2 * (NE + e)];
    atomicAdd(&cnt[d], 1);
}

__global__ void k_scanblk(const int* __restrict__ cnt, int* off, int* bsum) {
    __shared__ int tmp[1024];
    int i = blockIdx.x * 1024 + threadIdx.x;
    int v = (i < NN) ? cnt[i] : 0;
    tmp[threadIdx.x] = v;
    __syncthreads();
    for (int d = 1; d < 1024; d <<= 1) {
        int t = (threadIdx.x >= d) ? tmp[threadIdx.x - d] : 0;
        __syncthreads();
        tmp[threadIdx.x] += t;
        __syncthreads();
    }
    if (i < NN) off[i + 1] = tmp[threadIdx.x];
    if (threadIdx.x == 1023) bsum[blockIdx.x] = tmp[1023];
}

__global__ void k_scantop(int* bsum, int nb) {
    if (threadIdx.x == 0) {
        int run = 0;
        for (int b = 0; b < nb; b++) { int t = bsum[b]; bsum[b] = run; run += t; }
    }
}

__global__ void k_scanadd(int* off, const int* __restrict__ bsum) {
    int i = blockIdx.x * 1024 + threadIdx.x;
    if (i < NN) off[i + 1] += bsum[blockIdx.x];
    if (i == 0) off[0] = 0;
}

__global__ void k_scatter(const int* __restrict__ ei, const int* __restrict__ flag,
                          int* cursor, int* csr) {
    int e = blockIdx.x * 256 + threadIdx.x;
    if (e >= NE) return;
    int is32 = *flag;
    int s = is32 ? ei[e] : ei[2 * e];
    int d = is32 ? ei[NE + e] : ei[2 * (NE + e)];
    int pos = atomicAdd(&cursor[d], 1);
    csr[pos] = s;
}

// ---------------- x transpose: xT[t][n][20] for coalesced float4 staging ----------------
__global__ void k_xt(const float* __restrict__ x, float* __restrict__ xT) {
    int i = blockIdx.x * 256 + threadIdx.x;   // n*20 + kk
    if (i >= NN * 20) return;
    int n = i / 20, kk = i - n * 20;
    const float* xp = x + (size_t)n * 240 + (10 + kk) * 8;  // 8 contiguous t-values
    float4 a = *(const float4*)xp;
    float4 b = *(const float4*)(xp + 4);
    float v[8] = {a.x, a.y, a.z, a.w, b.x, b.y, b.z, b.w};
#pragma unroll
    for (int t = 0; t < 8; t++) xT[(size_t)t * NN * 20 + i] = v[t];
}

// ---------------- fold weights: WgT [KPAD][320], bg[320] ----------------
// cols 0..255: gates (W_ih folded through W_rel/W_root + W_hh); cols 256..319: gnn out
__global__ void k_prep(const float* __restrict__ W_ih, const float* __restrict__ W_hh,
                       const float* __restrict__ b_ih, const float* __restrict__ b_hh,
                       const float* __restrict__ W_rel, const float* __restrict__ b_rel,
                       const float* __restrict__ W_root, float* WgT, float* bg) {
    int j = threadIdx.x;          // 0..319
    int k = blockIdx.x;           // 0..159 => WgT row; 160 => bias
    if (k < KPAD) {
        float v = 0.f;
        if (j < 256) {
            if (k < 20) {
                v = W_ih[j * 84 + k];
            } else if (k < 84) {
                int kk = k - 20;
                float a = 0.f;
                for (int m = 0; m < 64; m++) a += W_ih[j * 84 + 20 + m] * W_rel[m * 64 + kk];
                v = a;
            } else if (k < 148) {
                int kk = k - 84;
                float a = W_hh[j * 64 + kk];
                for (int m = 0; m < 64; m++) a += W_ih[j * 84 + 20 + m] * W_root[m * 64 + kk];
                v = a;
            }
        } else {
            int j2 = j - 256;
            if (k >= 20 && k < 84) v = W_rel[j2 * 64 + (k - 20)];
            else if (k >= 84 && k < 148) v = W_root[j2 * 64 + (k - 84)];
        }
        WgT[k * JWFULL + j] = v;
    } else {
        if (j < 256) {
            float a = b_ih[j] + b_hh[j];
            for (int m = 0; m < 64; m++) a += W_ih[j * 84 + 20 + m] * b_rel[m];
            bg[j] = a;
        } else {
            bg[j] = b_rel[j - 256];
        }
    }
}

// ---------------- segment sum: wave per dst node, quarter-wave per edge (4 rows + 2x unroll = 8 in flight) ----------------
__global__ __launch_bounds__(256) void k_gather(const int* __restrict__ off,
                                                const int* __restrict__ csr,
                                                const float* __restrict__ h,
                                                float* __restrict__ agg) {
    int w = ((blockIdx.x * 256 + threadIdx.x) >> 6);
    if (w >= NN) return;
    int lane = threadIdx.x & 63;
    int q = lane >> 4, l16 = lane & 15;
    int e0 = off[w], e1 = off[w + 1];
    float4 a0 = make_float4(0.f, 0.f, 0.f, 0.f);
    float4 a1 = make_float4(0.f, 0.f, 0.f, 0.f);
    int e = e0 + q;
    for (; e + 4 < e1; e += 8) {
        int s0 = csr[e], s1 = csr[e + 4];
        float4 v0 = *(const float4*)(h + (size_t)s0 * 64 + l16 * 4);
        float4 v1 = *(const float4*)(h + (size_t)s1 * 64 + l16 * 4);
        a0.x += v0.x; a0.y += v0.y; a0.z += v0.z; a0.w += v0.w;
        a1.x += v1.x; a1.y += v1.y; a1.z += v1.z; a1.w += v1.w;
    }
    if (e < e1) {
        int s0 = csr[e];
        float4 v0 = *(const float4*)(h + (size_t)s0 * 64 + l16 * 4);
        a0.x += v0.x; a0.y += v0.y; a0.z += v0.z; a0.w += v0.w;
    }
    a0.x += a1.x; a0.y += a1.y; a0.z += a1.z; a0.w += a1.w;
#pragma unroll
    for (int d = 16; d < 64; d <<= 1) {
        a0.x += __shfl_xor(a0.x, d, 64);
        a0.y += __shfl_xor(a0.y, d, 64);
        a0.z += __shfl_xor(a0.z, d, 64);
        a0.w += __shfl_xor(a0.w, d, 64);
    }
    if (q == 0) *(float4*)(agg + (size_t)w * 64 + l16 * 4) = a0;
}

// ---------------- fused gates GEMM + LSTM cell (+ gnn outputs at t=T-1) ----------------
// tile: 64 nodes x JW outputs, K=160 (BK=40 x 4)
template <bool GNN>
__global__ __launch_bounds__(256) void k_gates(const float* __restrict__ x,
                                               const float* __restrict__ xT,
                                               const float* __restrict__ agg,
                                               float* __restrict__ h, float* __restrict__ c,
                                               const float* __restrict__ WgT,
                                               const float* __restrict__ bg,
                                               float* __restrict__ gnn, int t) {
    constexpr int G = GNN ? 5 : 4;
    constexpr int JW = GNN ? 320 : 256;
    __shared__ __align__(16) float Zs[64 * 44];   // node-major, stride 44 (pad)
    __shared__ __align__(16) float Ws[40 * JW];   // k-major
    const int tid = threadIdx.x;
    const int nblk = blockIdx.x * 64;
    const int ng = tid >> 4;
    const int jb4 = (tid & 15) * 4;

    float acc[G][4][4];   // [group][q][node]
#pragma unroll
    for (int g = 0; g < G; g++)
#pragma unroll
        for (int q = 0; q < 4; q++)
#pragma unroll
            for (int r = 0; r < 4; r++) acc[g][q][r] = 0.f;

    for (int kt = 0; kt < 4; ++kt) {
        __syncthreads();
        // stage W tile (40 x JW)
        for (int s = tid; s < 40 * (JW / 4); s += 256) {
            int k = s / (JW / 4), jq = s - k * (JW / 4);
            *(float4*)(Ws + k * JW + jq * 4) =
                *(const float4*)(WgT + (size_t)(kt * 40 + k) * JWFULL + jq * 4);
        }
        // stage Z tile (64 nodes x 40 k) from x / agg / h
        for (int s = 0; s < 3; ++s) {
            int slot = tid + 256 * s;
            if (slot < 640) {
                int n = slot / 10, kq = slot - n * 10;
                int n_g = nblk + n;
                int kk4 = kt * 40 + kq * 4;
                float4 z = make_float4(0.f, 0.f, 0.f, 0.f);
                if (n_g < NN) {
                    if (kk4 < 20) {
                        if (xT) {
                            z = *(const float4*)(xT + (size_t)t * NN * 20 + (size_t)n_g * 20 + kk4);
                        } else {
                            const float* xp = x + (size_t)n_g * 240 + (10 + kk4) * 8 + t;
                            z.x = xp[0]; z.y = xp[8]; z.z = xp[16]; z.w = xp[24];
                        }
                    } else if (kk4 < 84) {
                        z = *(const float4*)(agg + (size_t)n_g * 64 + (kk4 - 20));
                    } else if (kk4 < 148) {
                        z = *(const float4*)(h + (size_t)n_g * 64 + (kk4 - 84));
                    }
                }
                *(float4*)(Zs + n * 44 + kq * 4) = z;
            }
        }
        __syncthreads();
#pragma unroll 4
        for (int k = 0; k < 40; ++k) {
            float zr[4];
#pragma unroll
            for (int r = 0; r < 4; r++) zr[r] = Zs[(ng * 4 + r) * 44 + k];
#pragma unroll
            for (int g = 0; g < G; ++g) {
                float4 w = *(const float4*)(Ws + k * JW + g * 64 + jb4);
#pragma unroll
                for (int r = 0; r < 4; r++) {
                    acc[g][0][r] += zr[r] * w.x;
                    acc[g][1][r] += zr[r] * w.y;
                    acc[g][2][r] += zr[r] * w.z;
                    acc[g][3][r] += zr[r] * w.w;
                }
            }
        }
    }
    // epilogue — thread owns full i,f,g,o (and gnn if GNN) for its (node, j) pairs
#pragma unroll
    for (int r = 0; r < 4; ++r) {
        int n_g = nblk + ng * 4 + r;
        if (n_g >= NN) continue;
        float4 cold = *(const float4*)(c + (size_t)n_g * 64 + jb4);
        float co[4] = {cold.x, cold.y, cold.z, cold.w};
        float cn[4], hn[4];
#pragma unroll
        for (int q = 0; q < 4; ++q) {
            int j = jb4 + q;
            float iv = sigf(acc[0][q][r] + bg[j]);
            float fv = sigf(acc[1][q][r] + bg[64 + j]);
            float gv = tanhf_(acc[2][q][r] + bg[128 + j]);
            float ov = sigf(acc[3][q][r] + bg[192 + j]);
            cn[q] = fv * co[q] + iv * gv;
            hn[q] = ov * tanhf_(cn[q]);
        }
        if (GNN) {
            float4 gvv;
            gvv.x = acc[G - 1][0][r] + bg[256 + jb4 + 0];
            gvv.y = acc[G - 1][1][r] + bg[256 + jb4 + 1];
            gvv.z = acc[G - 1][2][r] + bg[256 + jb4 + 2];
            gvv.w = acc[G - 1][3][r] + bg[256 + jb4 + 3];
            *(float4*)(gnn + (size_t)n_g * 64 + jb4) = gvv;
        }
        *(float4*)(c + (size_t)n_g * 64 + jb4) = make_float4(cn[0], cn[1], cn[2], cn[3]);
        *(float4*)(h + (size_t)n_g * 64 + jb4) = make_float4(hn[0], hn[1], hn[2], hn[3]);
    }
}

// ---------------- batch-norm stats over N per feature ----------------
__global__ void k_stats(const float* __restrict__ h, const float* __restrict__ gnn,
                        float* sums, float* sumsq) {
    int f = threadIdx.x;                       // 0..127
    const float* base = (f < 64) ? h : gnn;
    int ff = f & 63;
    float s = 0.f, s2 = 0.f;
    for (int n = blockIdx.x; n < NN; n += gridDim.x) {
        float v = base[(size_t)n * 64 + ff];
        s += v; s2 += v * v;
    }
    atomicAdd(&sums[f], s);
    atomicAdd(&sumsq[f], s2);
}

__global__ void k_normprep(const float* __restrict__ sums, const float* __restrict__ sumsq,
                           const float* __restrict__ gamma, const float* __restrict__ beta,
                           float* ab) {
    int f = threadIdx.x;   // 128
    float mean = sums[f] / (float)NN;
    float var = sumsq[f] / (float)NN - mean * mean;
    float a = gamma[f] * rsqrtf(var + 1e-5f);
    ab[f] = a;
    ab[128 + f] = beta[f] - mean * a;
}

// ---------------- h1 = relu(normed @ W1.T + b1), wave per node ----------------
__global__ __launch_bounds__(256) void k_h1(const float* __restrict__ h,
                                            const float* __restrict__ gnn,
                                            const float* __restrict__ ab,
                                            const float* __restrict__ W1,
                                            const float* __restrict__ b1, float* h1) {
    __shared__ float W1T[128 * 66];
    __shared__ float fr[4][128];
    int tid = threadIdx.x, w = tid >> 6, lane = tid & 63;
    for (int idx = tid; idx < 64 * 128; idx += 256) {
        int j = idx >> 7, k = idx & 127;
        W1T[k * 66 + j] = W1[idx];
    }
    __syncthreads();
    float bb = b1[lane];
    for (int n = blockIdx.x * 4 + w; n < NN; n += gridDim.x * 4) {
        float v0 = h[(size_t)n * 64 + lane] * ab[lane] + ab[128 + lane];
        float v1 = gnn[(size_t)n * 64 + lane] * ab[64 + lane] + ab[192 + lane];
        fr[w][lane] = v0;
        fr[w][64 + lane] = v1;
        __threadfence_block();
        float a = bb;
#pragma unroll 8
        for (int k = 0; k < 128; k++) a += fr[w][k] * W1T[k * 66 + lane];
        h1[(size_t)n * 64 + lane] = fmaxf(a, 0.f);
        __threadfence_block();
    }
}

// ---------------- out = sigmoid(relu(h1@W2.T+b2) @ W_out.T + b_out) ----------------
__global__ __launch_bounds__(256) void k_out(const float* __restrict__ h1,
                                             const float* __restrict__ W2,
                                             const float* __restrict__ b2,
                                             const float* __restrict__ W_out,
                                             const float* __restrict__ b_out,
                                             float* __restrict__ out) {
    __shared__ float W2T[64 * 130];
    __shared__ float hb[4][64];
    int tid = threadIdx.x, w = tid >> 6, lane = tid & 63;
    for (int idx = tid; idx < 128 * 64; idx += 256) {
        int jj = idx >> 6, k = idx & 63;
        W2T[k * 130 + jj] = W2[idx];
    }
    __syncthreads();
    float wo0 = W_out[lane], wo1 = W_out[64 + lane];
    float bb0 = b2[lane], bb1 = b2[64 + lane], bo = b_out[0];
    for (int n = blockIdx.x * 4 + w; n < NN; n += gridDim.x * 4) {
        hb[w][lane] = h1[(size_t)n * 64 + lane];
        __threadfence_block();
        float a0 = bb0, a1 = bb1;
#pragma unroll 8
        for (int k = 0; k < 64; k++) {
            float hv = hb[w][k];
            a0 += hv * W2T[k * 130 + lane];
            a1 += hv * W2T[k * 130 + 64 + lane];
        }
        float p = fmaxf(a0, 0.f) * wo0 + fmaxf(a1, 0.f) * wo1;
        for (int o2 = 32; o2; o2 >>= 1) p += __shfl_down(p, o2, 64);
        if (lane == 0) out[n] = sigf(p + bo);
        __threadfence_block();
    }
}

extern "C" void kernel_launch(void* const* d_in, const int* in_sizes, int n_in,
                              void* d_out, int out_size, void* d_ws, size_t ws_size,
                              hipStream_t stream) {
    const float* x      = (const float*)d_in[0];
    const int*   ei     = (const int*)d_in[1];
    const float* W_ih   = (const float*)d_in[4];
    const float* W_hh   = (const float*)d_in[5];
    const float* b_ih   = (const float*)d_in[6];
    const float* b_hh   = (const float*)d_in[7];
    const float* W_rel  = (const float*)d_in[8];
    const float* b_rel  = (const float*)d_in[9];
    const float* W_root = (const float*)d_in[10];
    const float* gamma  = (const float*)d_in[11];
    const float* beta   = (const float*)d_in[12];
    const float* W1     = (const float*)d_in[13];
    const float* b1     = (const float*)d_in[14];
    const float* W2     = (const float*)d_in[15];
    const float* b2     = (const float*)d_in[16];
    const float* W_out  = (const float*)d_in[17];
    const float* b_out  = (const float*)d_in[18];
    float* out = (float*)d_out;

    char* ws = (char*)d_ws;
    size_t o = 0;
    auto carve = [&](size_t bytes) { char* p = ws + o; o += (bytes + 255) & ~(size_t)255; return p; };
    int*   off    = (int*)carve((NN + 1) * 4);
    int*   cnt    = (int*)carve(NN * 4);          // reused as cursor
    int*   bsum   = (int*)carve(128 * 4);
    int*   flag   = (int*)carve(256);
    int*   csr    = (int*)carve((size_t)NE * 4);
    float* h      = (float*)carve((size_t)NN * 64 * 4);
    float* c      = (float*)carve((size_t)NN * 64 * 4);
    float* agg    = (float*)carve((size_t)NN * 64 * 4);   // later reused as h1
    float* gnn    = (float*)carve((size_t)NN * 64 * 4);
    float* WgT    = (float*)carve((size_t)KPAD * JWFULL * 4);
    float* bg     = (float*)carve(JWFULL * 4);
    float* sums   = (float*)carve(128 * 4);
    float* sumsq  = (float*)carve(128 * 4);
    float* ab     = (float*)carve(256 * 4);
    float* h1     = agg;
    // optional x transpose buffer (guarded on ws_size)
    float* xT = nullptr;
    size_t need_xt = (size_t)TT * NN * 20 * 4;
    if (o + need_xt + 256 <= ws_size) xT = (float*)carve(need_xt);

    const int nscan = (NN + 1023) / 1024;   // 98

    // edge dtype detect + CSR build
    hipMemsetAsync(flag, 0, 4, stream);
    hipMemsetAsync(cnt, 0, NN * 4, stream);
    k_detect<<<16, 256, 0, stream>>>(ei, flag);
    k_hist<<<(NE + 255) / 256, 256, 0, stream>>>(ei, flag, cnt);
    k_scanblk<<<nscan, 1024, 0, stream>>>(cnt, off, bsum);
    k_scantop<<<1, 64, 0, stream>>>(bsum, nscan);
    k_scanadd<<<nscan, 1024, 0, stream>>>(off, bsum);
    hipMemcpyAsync(cnt, off, NN * 4, hipMemcpyDeviceToDevice, stream);  // cursor = off
    k_scatter<<<(NE + 255) / 256, 256, 0, stream>>>(ei, flag, cnt, csr);

    // init state + folded weights (+ x transpose)
    hipMemsetAsync(h, 0, (size_t)NN * 64 * 4 * 2, stream);   // h and c (contiguous)
    k_prep<<<KPAD + 1, JWFULL, 0, stream>>>(W_ih, W_hh, b_ih, b_hh, W_rel, b_rel, W_root, WgT, bg);
    if (xT) k_xt<<<(NN * 20 + 255) / 256, 256, 0, stream>>>(x, xT);

    // 8 recurrent steps (gnn fused into the last gates launch)
    const int ngates = (NN + 63) / 64;
    for (int t = 0; t < TT; ++t) {
        if (t == 0)
            hipMemsetAsync(agg, 0, (size_t)NN * 64 * 4, stream);   // h==0 => agg==0
        else
            k_gather<<<(NN + 3) / 4, 256, 0, stream>>>(off, csr, h, agg);
        if (t == TT - 1)
            k_gates<true><<<ngates, 256, 0, stream>>>(x, xT, agg, h, c, WgT, bg, gnn, t);
        else
            k_gates<false><<<ngates, 256, 0, stream>>>(x, xT, agg, h, c, WgT, bg, nullptr, t);
    }

    // batch-norm stats + head
    hipMemsetAsync(sums, 0, 256 * 4, stream);
    k_stats<<<1024, 128, 0, stream>>>(h, gnn, sums, sumsq);
    k_normprep<<<1, 128, 0, stream>>>(sums, sumsq, gamma, beta, ab);
    k_h1<<<1024, 256, 0, stream>>>(h, gnn, ab, W1, b1, h1);
    k_out<<<1024, 256, 0, stream>>>(h1, W2, b2, W_out, b_out, out);
}

// Round 3
// 1275.004 us; speedup vs baseline: 2.1664x; 1.9179x over previous
//
#include <hip/hip_runtime.h>

#define NN 100000
#define NE 1600000
#define TT 8
#define KF 160        // padded K: x 0..19 | pad 20..23 | agg 24..87 | h 88..151 | pad 152..159
#define XSTR 24       // xT row stride (20 + 4 zero pad), bf16

typedef __attribute__((ext_vector_type(8))) short bf16x8;
typedef __attribute__((ext_vector_type(4))) float f32x4;
typedef unsigned int uint_;
typedef unsigned short ushort_;

__device__ __forceinline__ float sigf(float x) { return 1.f / (1.f + __expf(-x)); }
__device__ __forceinline__ float tanhf_(float x) { return 1.f - 2.f / (__expf(2.f * x) + 1.f); }
__device__ __forceinline__ ushort_ f2b(float f) {
    uint_ u = __float_as_uint(f);
    u += 0x7fff + ((u >> 16) & 1);
    return (ushort_)(u >> 16);
}
__device__ __forceinline__ float bl(uint_ u) { return __uint_as_float(u << 16); }
__device__ __forceinline__ float bh(uint_ u) { return __uint_as_float(u & 0xffff0000u); }

// ---------------- edge dtype detect: int64 => odd int32 words are all 0 ----------------
__global__ void k_detect(const int* __restrict__ ei, int* flag) {
    int i = blockIdx.x * 256 + threadIdx.x;
    if (ei[2 * i + 1] != 0) atomicOr(flag, 1);
}

// ---------------- CSR build ----------------
__global__ void k_hist(const int* __restrict__ ei, const int* __restrict__ flag, int* cnt) {
    int e = blockIdx.x * 256 + threadIdx.x;
    if (e >= NE) return;
    int is32 = *flag;
    int d = is32 ? ei[NE + e] : ei[2 * (NE + e)];
    atomicAdd(&cnt[d], 1);
}

__global__ void k_scanblk(const int* __restrict__ cnt, int* off, int* bsum) {
    __shared__ int tmp[1024];
    int i = blockIdx.x * 1024 + threadIdx.x;
    int v = (i < NN) ? cnt[i] : 0;
    tmp[threadIdx.x] = v;
    __syncthreads();
    for (int d = 1; d < 1024; d <<= 1) {
        int t = (threadIdx.x >= d) ? tmp[threadIdx.x - d] : 0;
        __syncthreads();
        tmp[threadIdx.x] += t;
        __syncthreads();
    }
    if (i < NN) off[i + 1] = tmp[threadIdx.x];
    if (threadIdx.x == 1023) bsum[blockIdx.x] = tmp[1023];
}

__global__ void k_scantop(int* bsum, int nb) {
    if (threadIdx.x == 0) {
        int run = 0;
        for (int b = 0; b < nb; b++) { int t = bsum[b]; bsum[b] = run; run += t; }
    }
}

__global__ void k_scanadd(int* off, const int* __restrict__ bsum) {
    int i = blockIdx.x * 1024 + threadIdx.x;
    if (i < NN) off[i + 1] += bsum[blockIdx.x];
    if (i == 0) off[0] = 0;
}

__global__ void k_scatter(const int* __restrict__ ei, const int* __restrict__ flag,
                          int* cursor, int* csr) {
    int e = blockIdx.x * 256 + threadIdx.x;
    if (e >= NE) return;
    int is32 = *flag;
    int s = is32 ? ei[e] : ei[2 * e];
    int d = is32 ? ei[NE + e] : ei[2 * (NE + e)];
    int pos = atomicAdd(&cursor[d], 1);
    csr[pos] = s;
}

// ---------------- x transpose -> bf16 planes xT[t][n][24] ----------------
__global__ void k_xt(const float* __restrict__ x, ushort_* __restrict__ xT) {
    int i = blockIdx.x * 256 + threadIdx.x;   // n*24 + kk
    if (i >= NN * XSTR) return;
    int n = i / XSTR, kk = i - n * XSTR;
    if (kk < 20) {
        const float* xp = x + (size_t)n * 240 + (10 + kk) * 8;  // 8 contiguous t
#pragma unroll
        for (int t = 0; t < 8; t++) xT[(size_t)t * NN * XSTR + i] = f2b(xp[t]);
    } else {
#pragma unroll
        for (int t = 0; t < 8; t++) xT[(size_t)t * NN * XSTR + i] = 0;
    }
}

// ---------------- fold weights into WgB bf16 [n=320][KF], gate-interleaved cols ----------------
// col n<256: wave w=n>>6, gate=(n>>4)&3, j=w*16+(n&15), row=gate*64+j
// col n>=256: gnn output j=n-256
__global__ void k_prep(const float* __restrict__ W_ih, const float* __restrict__ W_hh,
                       const float* __restrict__ b_ih, const float* __restrict__ b_hh,
                       const float* __restrict__ W_rel, const float* __restrict__ b_rel,
                       const float* __restrict__ W_root, ushort_* WgB, float* bgp) {
    int n = threadIdx.x;          // 0..319
    int k = blockIdx.x;           // 0..159 rows; 160 => bias
    if (k < KF) {
        float v = 0.f;
        if (n < 256) {
            int w = n >> 6, g = (n >> 4) & 3, j = w * 16 + (n & 15);
            int row = g * 64 + j;
            if (k < 20) {
                v = W_ih[row * 84 + k];
            } else if (k >= 24 && k < 88) {
                int kk = k - 24;
                float a = 0.f;
                for (int m = 0; m < 64; m++) a += W_ih[row * 84 + 20 + m] * W_rel[m * 64 + kk];
                v = a;
            } else if (k >= 88 && k < 152) {
                int kk = k - 88;
                float a = W_hh[row * 64 + kk];
                for (int m = 0; m < 64; m++) a += W_ih[row * 84 + 20 + m] * W_root[m * 64 + kk];
                v = a;
            }
        } else {
            int j = n - 256;
            if (k >= 24 && k < 88) v = W_rel[j * 64 + (k - 24)];
            else if (k >= 88 && k < 152) v = W_root[j * 64 + (k - 88)];
        }
        WgB[(size_t)n * KF + k] = f2b(v);
    } else {
        if (n < 256) {
            int j = n >> 2, g = n & 3;            // bgp[j*4+g]
            int row = g * 64 + j;
            float a = b_ih[row] + b_hh[row];
            for (int m = 0; m < 64; m++) a += W_ih[row * 84 + 20 + m] * b_rel[m];
            bgp[n] = a;
        } else {
            bgp[n] = b_rel[n - 256];
        }
    }
}

// ---------------- segment sum over bf16 h: wave per dst node, eighth-wave per edge ----------------
__global__ __launch_bounds__(256) void k_gather(const int* __restrict__ off,
                                                const int* __restrict__ csr,
                                                const ushort_* __restrict__ hb,
                                                ushort_* __restrict__ aggb) {
    int w = ((blockIdx.x * 256 + threadIdx.x) >> 6);
    if (w >= NN) return;
    int lane = threadIdx.x & 63;
    int oct = lane >> 3, l8 = lane & 7;
    int e0 = off[w], e1 = off[w + 1];
    float a0[8], a1[8];
#pragma unroll
    for (int i = 0; i < 8; i++) { a0[i] = 0.f; a1[i] = 0.f; }
    int e = e0 + oct;
    for (; e + 8 < e1; e += 16) {
        int s0 = csr[e], s1 = csr[e + 8];
        uint4 v0 = *(const uint4*)(hb + (size_t)s0 * 64 + l8 * 8);
        uint4 v1 = *(const uint4*)(hb + (size_t)s1 * 64 + l8 * 8);
        a0[0] += bl(v0.x); a0[1] += bh(v0.x); a0[2] += bl(v0.y); a0[3] += bh(v0.y);
        a0[4] += bl(v0.z); a0[5] += bh(v0.z); a0[6] += bl(v0.w); a0[7] += bh(v0.w);
        a1[0] += bl(v1.x); a1[1] += bh(v1.x); a1[2] += bl(v1.y); a1[3] += bh(v1.y);
        a1[4] += bl(v1.z); a1[5] += bh(v1.z); a1[6] += bl(v1.w); a1[7] += bh(v1.w);
    }
    if (e < e1) {
        int s0 = csr[e];
        uint4 v0 = *(const uint4*)(hb + (size_t)s0 * 64 + l8 * 8);
        a0[0] += bl(v0.x); a0[1] += bh(v0.x); a0[2] += bl(v0.y); a0[3] += bh(v0.y);
        a0[4] += bl(v0.z); a0[5] += bh(v0.z); a0[6] += bl(v0.w); a0[7] += bh(v0.w);
    }
#pragma unroll
    for (int i = 0; i < 8; i++) a0[i] += a1[i];
#pragma unroll
    for (int d = 8; d < 64; d <<= 1)
#pragma unroll
        for (int i = 0; i < 8; i++) a0[i] += __shfl_xor(a0[i], d, 64);
    if (oct == 0) {
        uint4 o;
        o.x = (uint_)f2b(a0[0]) | ((uint_)f2b(a0[1]) << 16);
        o.y = (uint_)f2b(a0[2]) | ((uint_)f2b(a0[3]) << 16);
        o.z = (uint_)f2b(a0[4]) | ((uint_)f2b(a0[5]) << 16);
        o.w = (uint_)f2b(a0[6]) | ((uint_)f2b(a0[7]) << 16);
        *(uint4*)(aggb + (size_t)w * 64 + l8 * 8) = o;
    }
}

// ---------------- MFMA gates GEMM + LSTM cell (+ gnn/h-fp32 at t=T-1) ----------------
// M-tile 64 nodes, N = 256 (320 w/ gnn), K = 160 (5 x 32). 4 waves: wave w owns n [w*64,w*64+64)
// (+ gnn tile n [256+w*16, +16)). Gate-interleaved cols => thread holds i,f,g,o for one j.
template <bool LAST>
__global__ __launch_bounds__(256) void k_gates(const float* __restrict__ x,
                                               const ushort_* __restrict__ xT,
                                               const ushort_* __restrict__ aggb,
                                               ushort_* __restrict__ hb,
                                               float* __restrict__ hf,
                                               float* __restrict__ c,
                                               const ushort_* __restrict__ WgB,
                                               const float* __restrict__ bgp,
                                               float* __restrict__ gnn, int t) {
    constexpr int JW = LAST ? 320 : 256;
    constexpr int NT = LAST ? 5 : 4;
    __shared__ __align__(16) ushort_ Zs[64 * 168];   // [node][KF pad 168]
    __shared__ __align__(16) ushort_ Ws[JW * 40];    // per-kt [n][32 pad 40]
    const int tid = threadIdx.x;
    const int nblk = blockIdx.x * 64;
    const int w = tid >> 6, lane = tid & 63;
    const int q = lane >> 4, l16 = lane & 15;

    // ---- stage Z (64 x KF bf16), once ----
#pragma unroll
    for (int i = 0; i < 5; ++i) {
        int slot = tid + 256 * i;               // node*20 + oct
        int n = slot / 20, oct = slot - n * 20;
        int n_g = nblk + n;
        uint4 z = make_uint4(0, 0, 0, 0);
        if (n_g < NN) {
            if (oct < 3) {
                if (xT) {
                    z = *(const uint4*)(xT + ((size_t)t * NN + n_g) * XSTR + oct * 8);
                } else {
                    const float* xp = x + (size_t)n_g * 240 + 80 + (size_t)oct * 64 + t;
                    uint_ r[4];
#pragma unroll
                    for (int p = 0; p < 4; p++) {
                        int k0 = oct * 8 + p * 2;
                        ushort_ b0 = (k0 < 20) ? f2b(xp[p * 16]) : (ushort_)0;
                        ushort_ b1 = (k0 + 1 < 20) ? f2b(xp[p * 16 + 8]) : (ushort_)0;
                        r[p] = (uint_)b0 | ((uint_)b1 << 16);
                    }
                    z = make_uint4(r[0], r[1], r[2], r[3]);
                }
            } else if (oct < 11) {
                z = *(const uint4*)(aggb + (size_t)n_g * 64 + (oct - 3) * 8);
            } else if (oct < 19) {
                z = *(const uint4*)(hb + (size_t)n_g * 64 + (oct - 11) * 8);
            }
        }
        *(uint4*)(Zs + n * 168 + oct * 8) = z;
    }

    f32x4 acc[4][NT];
#pragma unroll
    for (int mt = 0; mt < 4; mt++)
#pragma unroll
        for (int nt = 0; nt < NT; nt++) acc[mt][nt] = (f32x4)(0.f);

    for (int kt = 0; kt < 5; ++kt) {
        __syncthreads();
        // stage W chunk [JW][32]
#pragma unroll
        for (int i = 0; i < JW / 64; ++i) {
            int slot = tid + 256 * i;
            int n = slot >> 2, oct = slot & 3;
            uint4 v = *(const uint4*)(WgB + (size_t)n * KF + kt * 32 + oct * 8);
            *(uint4*)(Ws + n * 40 + oct * 8) = v;
        }
        __syncthreads();
        bf16x8 af[4], bf[NT];
#pragma unroll
        for (int mt = 0; mt < 4; mt++)
            af[mt] = *(const bf16x8*)(Zs + (mt * 16 + l16) * 168 + kt * 32 + q * 8);
#pragma unroll
        for (int nt = 0; nt < NT; nt++) {
            int n = (nt < 4) ? (w * 64 + nt * 16 + l16) : (256 + w * 16 + l16);
            bf[nt] = *(const bf16x8*)(Ws + n * 40 + q * 8);
        }
#pragma unroll
        for (int mt = 0; mt < 4; mt++)
#pragma unroll
            for (int nt = 0; nt < NT; nt++)
                acc[mt][nt] = __builtin_amdgcn_mfma_f32_16x16x32_bf16(af[mt], bf[nt], acc[mt][nt], 0, 0, 0);
    }

    // ---- epilogue: thread holds gates i,f,g,o (nt=0..3) for j = w*16+l16, nodes mt*16+q*4+r ----
    const int j = w * 16 + l16;
    const f32x4 bias = *(const f32x4*)(bgp + j * 4);
    const float brl = LAST ? bgp[256 + j] : 0.f;
#pragma unroll
    for (int mt = 0; mt < 4; ++mt) {
#pragma unroll
        for (int r = 0; r < 4; ++r) {
            int node = nblk + mt * 16 + q * 4 + r;
            if (node >= NN) continue;
            size_t idx = (size_t)node * 64 + j;
            float iv = sigf(acc[mt][0][r] + bias.x);
            float fv = sigf(acc[mt][1][r] + bias.y);
            float gv = tanhf_(acc[mt][2][r] + bias.z);
            float ov = sigf(acc[mt][3][r] + bias.w);
            float cn = fv * c[idx] + iv * gv;
            float hn = ov * tanhf_(cn);
            c[idx] = cn;
            hb[idx] = f2b(hn);
            if (LAST) {
                hf[idx] = hn;
                gnn[idx] = acc[mt][4][r] + brl;
            }
        }
    }
}

// ---------------- batch-norm stats over N per feature ----------------
__global__ void k_stats(const float* __restrict__ h, const float* __restrict__ gnn,
                        float* sums, float* sumsq) {
    int f = threadIdx.x;                       // 0..127
    const float* base = (f < 64) ? h : gnn;
    int ff = f & 63;
    float s = 0.f, s2 = 0.f;
    for (int n = blockIdx.x; n < NN; n += gridDim.x) {
        float v = base[(size_t)n * 64 + ff];
        s += v; s2 += v * v;
    }
    atomicAdd(&sums[f], s);
    atomicAdd(&sumsq[f], s2);
}

__global__ void k_normprep(const float* __restrict__ sums, const float* __restrict__ sumsq,
                           const float* __restrict__ gamma, const float* __restrict__ beta,
                           float* ab) {
    int f = threadIdx.x;   // 128
    float mean = sums[f] / (float)NN;
    float var = sumsq[f] / (float)NN - mean * mean;
    float a = gamma[f] * rsqrtf(var + 1e-5f);
    ab[f] = a;
    ab[128 + f] = beta[f] - mean * a;
}

// ---------------- h1 = relu(normed @ W1.T + b1), wave per node ----------------
__global__ __launch_bounds__(256) void k_h1(const float* __restrict__ h,
                                            const float* __restrict__ gnn,
                                            const float* __restrict__ ab,
                                            const float* __restrict__ W1,
                                            const float* __restrict__ b1, float* h1) {
    __shared__ float W1T[128 * 66];
    __shared__ float fr[4][128];
    int tid = threadIdx.x, w = tid >> 6, lane = tid & 63;
    for (int idx = tid; idx < 64 * 128; idx += 256) {
        int j = idx >> 7, k = idx & 127;
        W1T[k * 66 + j] = W1[idx];
    }
    __syncthreads();
    float bb = b1[lane];
    for (int n = blockIdx.x * 4 + w; n < NN; n += gridDim.x * 4) {
        float v0 = h[(size_t)n * 64 + lane] * ab[lane] + ab[128 + lane];
        float v1 = gnn[(size_t)n * 64 + lane] * ab[64 + lane] + ab[192 + lane];
        fr[w][lane] = v0;
        fr[w][64 + lane] = v1;
        __threadfence_block();
        float a = bb;
#pragma unroll 8
        for (int k = 0; k < 128; k++) a += fr[w][k] * W1T[k * 66 + lane];
        h1[(size_t)n * 64 + lane] = fmaxf(a, 0.f);
        __threadfence_block();
    }
}

// ---------------- out = sigmoid(relu(h1@W2.T+b2) @ W_out.T + b_out) ----------------
__global__ __launch_bounds__(256) void k_out(const float* __restrict__ h1,
                                             const float* __restrict__ W2,
                                             const float* __restrict__ b2,
                                             const float* __restrict__ W_out,
                                             const float* __restrict__ b_out,
                                             float* __restrict__ out) {
    __shared__ float W2T[64 * 130];
    __shared__ float hbuf[4][64];
    int tid = threadIdx.x, w = tid >> 6, lane = tid & 63;
    for (int idx = tid; idx < 128 * 64; idx += 256) {
        int jj = idx >> 6, k = idx & 63;
        W2T[k * 130 + jj] = W2[idx];
    }
    __syncthreads();
    float wo0 = W_out[lane], wo1 = W_out[64 + lane];
    float bb0 = b2[lane], bb1 = b2[64 + lane], bo = b_out[0];
    for (int n = blockIdx.x * 4 + w; n < NN; n += gridDim.x * 4) {
        hbuf[w][lane] = h1[(size_t)n * 64 + lane];
        __threadfence_block();
        float a0 = bb0, a1 = bb1;
#pragma unroll 8
        for (int k = 0; k < 64; k++) {
            float hv = hbuf[w][k];
            a0 += hv * W2T[k * 130 + lane];
            a1 += hv * W2T[k * 130 + 64 + lane];
        }
        float p = fmaxf(a0, 0.f) * wo0 + fmaxf(a1, 0.f) * wo1;
        for (int o2 = 32; o2; o2 >>= 1) p += __shfl_down(p, o2, 64);
        if (lane == 0) out[n] = sigf(p + bo);
        __threadfence_block();
    }
}

extern "C" void kernel_launch(void* const* d_in, const int* in_sizes, int n_in,
                              void* d_out, int out_size, void* d_ws, size_t ws_size,
                              hipStream_t stream) {
    const float* x      = (const float*)d_in[0];
    const int*   ei     = (const int*)d_in[1];
    const float* W_ih   = (const float*)d_in[4];
    const float* W_hh   = (const float*)d_in[5];
    const float* b_ih   = (const float*)d_in[6];
    const float* b_hh   = (const float*)d_in[7];
    const float* W_rel  = (const float*)d_in[8];
    const float* b_rel  = (const float*)d_in[9];
    const float* W_root = (const float*)d_in[10];
    const float* gamma  = (const float*)d_in[11];
    const float* beta   = (const float*)d_in[12];
    const float* W1     = (const float*)d_in[13];
    const float* b1     = (const float*)d_in[14];
    const float* W2     = (const float*)d_in[15];
    const float* b2     = (const float*)d_in[16];
    const float* W_out  = (const float*)d_in[17];
    const float* b_out  = (const float*)d_in[18];
    float* out = (float*)d_out;

    char* ws = (char*)d_ws;
    size_t o = 0;
    auto carve = [&](size_t bytes) { char* p = ws + o; o += (bytes + 255) & ~(size_t)255; return p; };
    int*     off   = (int*)carve((NN + 1) * 4);
    int*     cnt   = (int*)carve(NN * 4);          // reused as cursor
    int*     bsum  = (int*)carve(128 * 4);
    int*     flag  = (int*)carve(256);
    int*     csr   = (int*)carve((size_t)NE * 4);
    float*   hf    = (float*)carve((size_t)NN * 64 * 4);   // fp32 h (written at t=7 only)
    float*   c     = (float*)carve((size_t)NN * 64 * 4);
    float*   gnn   = (float*)carve((size_t)NN * 64 * 4);
    float*   h1    = (float*)carve((size_t)NN * 64 * 4);
    ushort_* hb    = (ushort_*)carve((size_t)NN * 64 * 2); // bf16 h mirror
    ushort_* aggb  = (ushort_*)carve((size_t)NN * 64 * 2); // bf16 agg
    ushort_* WgB   = (ushort_*)carve((size_t)320 * KF * 2);
    float*   bgp   = (float*)carve(320 * 4);
    float*   sums  = (float*)carve(128 * 4);
    float*   sumsq = (float*)carve(128 * 4);
    float*   ab    = (float*)carve(256 * 4);
    // optional bf16 x-transpose (guarded on ws_size)
    ushort_* xT = nullptr;
    size_t need_xt = (size_t)TT * NN * XSTR * 2;
    if (o + need_xt + 256 <= ws_size) xT = (ushort_*)carve(need_xt);

    const int nscan = (NN + 1023) / 1024;   // 98

    // edge dtype detect + CSR build
    hipMemsetAsync(flag, 0, 4, stream);
    hipMemsetAsync(cnt, 0, NN * 4, stream);
    k_detect<<<16, 256, 0, stream>>>(ei, flag);
    k_hist<<<(NE + 255) / 256, 256, 0, stream>>>(ei, flag, cnt);
    k_scanblk<<<nscan, 1024, 0, stream>>>(cnt, off, bsum);
    k_scantop<<<1, 64, 0, stream>>>(bsum, nscan);
    k_scanadd<<<nscan, 1024, 0, stream>>>(off, bsum);
    hipMemcpyAsync(cnt, off, NN * 4, hipMemcpyDeviceToDevice, stream);  // cursor = off
    k_scatter<<<(NE + 255) / 256, 256, 0, stream>>>(ei, flag, cnt, csr);

    // init state + folded weights + x transpose
    hipMemsetAsync(c, 0, (size_t)NN * 64 * 4, stream);
    hipMemsetAsync(hb, 0, (size_t)NN * 64 * 2 * 2, stream);   // hb and aggb (contiguous carves)
    k_prep<<<KF + 1, 320, 0, stream>>>(W_ih, W_hh, b_ih, b_hh, W_rel, b_rel, W_root, WgB, bgp);
    if (xT) k_xt<<<(NN * XSTR + 255) / 256, 256, 0, stream>>>(x, xT);

    // 8 recurrent steps
    const int ngates = (NN + 63) / 64;
    for (int t = 0; t < TT; ++t) {
        if (t > 0)
            k_gather<<<(NN + 3) / 4, 256, 0, stream>>>(off, csr, hb, aggb);
        if (t == TT - 1)
            k_gates<true><<<ngates, 256, 0, stream>>>(x, xT, aggb, hb, hf, c, WgB, bgp, gnn, t);
        else
            k_gates<false><<<ngates, 256, 0, stream>>>(x, xT, aggb, hb, hf, c, WgB, bgp, nullptr, t);
    }

    // batch-norm stats + head
    hipMemsetAsync(sums, 0, 256 * 4, stream);
    k_stats<<<1024, 128, 0, stream>>>(hf, gnn, sums, sumsq);
    k_normprep<<<1, 128, 0, stream>>>(sums, sumsq, gamma, beta, ab);
    k_h1<<<1024, 256, 0, stream>>>(hf, gnn, ab, W1, b1, h1);
    k_out<<<1024, 256, 0, stream>>>(h1, W2, b2, W_out, b_out, out);
}

// Round 4
// 1204.481 us; speedup vs baseline: 2.2932x; 1.0586x over previous
//
#include <hip/hip_runtime.h>

#define NN 100000
#define NE 1600000
#define TT 8
#define KF 160        // padded K: x 0..19 | pad 20..23 | agg 24..87 | h 88..151 | pad 152..159
#define XSTR 24       // xT row stride (20 + 4 zero pad), bf16
#define HISTB 6250    // hist blocks in the merged hist+xt kernel

typedef __attribute__((ext_vector_type(8))) short bf16x8;
typedef __attribute__((ext_vector_type(4))) float f32x4;
typedef unsigned int uint_;
typedef unsigned short ushort_;

__device__ __forceinline__ float sigf(float x) { return 1.f / (1.f + __expf(-x)); }
__device__ __forceinline__ float tanhf_(float x) { return 1.f - 2.f / (__expf(2.f * x) + 1.f); }
__device__ __forceinline__ ushort_ f2b(float f) {
    uint_ u = __float_as_uint(f);
    u += 0x7fff + ((u >> 16) & 1);
    return (ushort_)(u >> 16);
}
__device__ __forceinline__ float bl(uint_ u) { return __uint_as_float(u << 16); }
__device__ __forceinline__ float bh(uint_ u) { return __uint_as_float(u & 0xffff0000u); }
__device__ __forceinline__ void acc8(float* a, uint4 v) {
    a[0] += bl(v.x); a[1] += bh(v.x); a[2] += bl(v.y); a[3] += bh(v.y);
    a[4] += bl(v.z); a[5] += bh(v.z); a[6] += bl(v.w); a[7] += bh(v.w);
}

// ---------------- edge dtype detect: int64 => odd int32 words are all 0 ----------------
__global__ void k_detect(const int* __restrict__ ei, int* flag) {
    int i = blockIdx.x * 256 + threadIdx.x;
    if (ei[2 * i + 1] != 0) atomicOr(flag, 1);
}

// ---------------- merged: dst histogram + x transpose (independent work, overlapped) ----------------
__global__ void k_hist_xt(const int* __restrict__ ei, const int* __restrict__ flag, int* cnt,
                          const float* __restrict__ x, ushort_* __restrict__ xT) {
    int b = blockIdx.x;
    if (b < HISTB) {
        int e = b * 256 + threadIdx.x;
        if (e >= NE) return;
        int is32 = *flag;
        int d = is32 ? ei[NE + e] : ei[2 * (NE + e)];
        atomicAdd(&cnt[d], 1);
    } else {
        if (!xT) return;
        int i = (b - HISTB) * 256 + threadIdx.x;   // n*24 + kk
        if (i >= NN * XSTR) return;
        int n = i / XSTR, kk = i - n * XSTR;
        if (kk < 20) {
            const float* xp = x + (size_t)n * 240 + (10 + kk) * 8;
#pragma unroll
            for (int t = 0; t < 8; t++) xT[(size_t)t * NN * XSTR + i] = f2b(xp[t]);
        } else {
#pragma unroll
            for (int t = 0; t < 8; t++) xT[(size_t)t * NN * XSTR + i] = 0;
        }
    }
}

// ---------------- CSR scan ----------------
__global__ void k_scanblk(const int* __restrict__ cnt, int* off, int* bsum) {
    __shared__ int tmp[1024];
    int i = blockIdx.x * 1024 + threadIdx.x;
    int v = (i < NN) ? cnt[i] : 0;
    tmp[threadIdx.x] = v;
    __syncthreads();
    for (int d = 1; d < 1024; d <<= 1) {
        int t = (threadIdx.x >= d) ? tmp[threadIdx.x - d] : 0;
        __syncthreads();
        tmp[threadIdx.x] += t;
        __syncthreads();
    }
    if (i < NN) off[i + 1] = tmp[threadIdx.x];
    if (threadIdx.x == 1023) bsum[blockIdx.x] = tmp[1023];
}

__global__ void k_scantop(int* bsum, int nb) {
    if (threadIdx.x == 0) {
        int run = 0;
        for (int b = 0; b < nb; b++) { int t = bsum[b]; bsum[b] = run; run += t; }
    }
}

__global__ void k_scanadd(int* off, const int* __restrict__ bsum) {
    int i = blockIdx.x * 1024 + threadIdx.x;
    if (i < NN) off[i + 1] += bsum[blockIdx.x];
    if (i == 0) off[0] = 0;
}

__global__ void k_scatter(const int* __restrict__ ei, const int* __restrict__ flag,
                          int* cursor, int* csr) {
    int e = blockIdx.x * 256 + threadIdx.x;
    if (e >= NE) return;
    int is32 = *flag;
    int s = is32 ? ei[e] : ei[2 * e];
    int d = is32 ? ei[NE + e] : ei[2 * (NE + e)];
    int pos = atomicAdd(&cursor[d], 1);
    csr[pos] = s;
}

// ---------------- fold weights into WgB bf16 [n=320][KF], gate-interleaved cols ----------------
__global__ void k_prep(const float* __restrict__ W_ih, const float* __restrict__ W_hh,
                       const float* __restrict__ b_ih, const float* __restrict__ b_hh,
                       const float* __restrict__ W_rel, const float* __restrict__ b_rel,
                       const float* __restrict__ W_root, ushort_* WgB, float* bgp) {
    int n = threadIdx.x;          // 0..319
    int k = blockIdx.x;           // 0..159 rows; 160 => bias
    if (k < KF) {
        float v = 0.f;
        if (n < 256) {
            int w = n >> 6, g = (n >> 4) & 3, j = w * 16 + (n & 15);
            int row = g * 64 + j;
            if (k < 20) {
                v = W_ih[row * 84 + k];
            } else if (k >= 24 && k < 88) {
                int kk = k - 24;
                float a = 0.f;
                for (int m = 0; m < 64; m++) a += W_ih[row * 84 + 20 + m] * W_rel[m * 64 + kk];
                v = a;
            } else if (k >= 88 && k < 152) {
                int kk = k - 88;
                float a = W_hh[row * 64 + kk];
                for (int m = 0; m < 64; m++) a += W_ih[row * 84 + 20 + m] * W_root[m * 64 + kk];
                v = a;
            }
        } else {
            int j = n - 256;
            if (k >= 24 && k < 88) v = W_rel[j * 64 + (k - 24)];
            else if (k >= 88 && k < 152) v = W_root[j * 64 + (k - 88)];
        }
        WgB[(size_t)n * KF + k] = f2b(v);
    } else {
        if (n < 256) {
            int j = n >> 2, g = n & 3;            // bgp[j*4+g]
            int row = g * 64 + j;
            float a = b_ih[row] + b_hh[row];
            for (int m = 0; m < 64; m++) a += W_ih[row * 84 + 20 + m] * b_rel[m];
            bgp[n] = a;
        } else {
            bgp[n] = b_rel[n - 256];
        }
    }
}

// ---------------- fused step: gather (CSR segment sum) + MFMA gates + LSTM cell ----------------
// M-tile 64 dst nodes, N = 256 (320 w/ gnn at t=7), K = 160 (5 x 32).
// Gather reads hbR (prev step's bf16 h), epilogue writes hbW — ping-pong avoids intra-launch races.
// LAST also: fp32 h + gnn outputs + BN partial sums via atomics.
template <bool LAST>
__global__ __launch_bounds__(256) void k_step(const float* __restrict__ x,
                                              const ushort_* __restrict__ xT,
                                              const int* __restrict__ off,
                                              const int* __restrict__ csr,
                                              const ushort_* __restrict__ hbR,
                                              ushort_* __restrict__ hbW,
                                              float* __restrict__ hf,
                                              float* __restrict__ c,
                                              const ushort_* __restrict__ WgB,
                                              const float* __restrict__ bgp,
                                              float* __restrict__ gnn,
                                              float* __restrict__ sums,
                                              float* __restrict__ sumsq, int t) {
    constexpr int JW = LAST ? 320 : 256;
    constexpr int NT = LAST ? 5 : 4;
    __shared__ __align__(16) ushort_ Zs[64 * 168];   // [node][KF pad 168]
    __shared__ __align__(16) ushort_ Ws[JW * 40];    // per-kt [n][32 pad 40]
    const int tid = threadIdx.x;
    const int nblk = blockIdx.x * 64;
    const int w = tid >> 6, lane = tid & 63;
    const int q = lane >> 4, l16 = lane & 15;

    // ---- stage x (octs 0..2), h (octs 11..18), zero-pad (oct 19): 64 nodes x 12 slots ----
#pragma unroll
    for (int i = 0; i < 3; ++i) {
        int slot = tid + 256 * i;
        int n = slot / 12, oo = slot - n * 12;
        int n_g = nblk + n;
        uint4 z = make_uint4(0, 0, 0, 0);
        if (n_g < NN) {
            if (oo < 3) {
                if (xT) {
                    z = *(const uint4*)(xT + ((size_t)t * NN + n_g) * XSTR + oo * 8);
                } else {
                    const float* xp = x + (size_t)n_g * 240 + 80 + (size_t)oo * 64 + t;
                    uint_ r[4];
#pragma unroll
                    for (int p = 0; p < 4; p++) {
                        int k0 = oo * 8 + p * 2;
                        ushort_ b0 = (k0 < 20) ? f2b(xp[p * 16]) : (ushort_)0;
                        ushort_ b1 = (k0 + 1 < 20) ? f2b(xp[p * 16 + 8]) : (ushort_)0;
                        r[p] = (uint_)b0 | ((uint_)b1 << 16);
                    }
                    z = make_uint4(r[0], r[1], r[2], r[3]);
                }
            } else if (oo < 11) {
                z = *(const uint4*)(hbR + (size_t)n_g * 64 + (oo - 3) * 8);
            }
        }
        int oct = (oo < 3) ? oo : ((oo < 11) ? (oo + 8) : 19);
        *(uint4*)(Zs + n * 168 + oct * 8) = z;
    }

    // ---- gather phase: oct-slot per node, lane l8 owns features l8*8..+7, fp32 accum ----
    {
        int slot = tid >> 3;       // 0..31
        int l8 = tid & 7;
        for (int nn = slot; nn < 64; nn += 32) {
            int node = nblk + nn;
            float a[8];
#pragma unroll
            for (int i = 0; i < 8; i++) a[i] = 0.f;
            if (t > 0 && node < NN) {
                int e0 = off[node], e1 = off[node + 1];
                int e = e0;
                for (; e + 4 <= e1; e += 4) {
                    int s0 = csr[e], s1 = csr[e + 1], s2 = csr[e + 2], s3 = csr[e + 3];
                    uint4 v0 = *(const uint4*)(hbR + (size_t)s0 * 64 + l8 * 8);
                    uint4 v1 = *(const uint4*)(hbR + (size_t)s1 * 64 + l8 * 8);
                    uint4 v2 = *(const uint4*)(hbR + (size_t)s2 * 64 + l8 * 8);
                    uint4 v3 = *(const uint4*)(hbR + (size_t)s3 * 64 + l8 * 8);
                    acc8(a, v0); acc8(a, v1); acc8(a, v2); acc8(a, v3);
                }
                for (; e < e1; e++) {
                    uint4 v0 = *(const uint4*)(hbR + (size_t)csr[e] * 64 + l8 * 8);
                    acc8(a, v0);
                }
            }
            uint4 o;
            o.x = (uint_)f2b(a[0]) | ((uint_)f2b(a[1]) << 16);
            o.y = (uint_)f2b(a[2]) | ((uint_)f2b(a[3]) << 16);
            o.z = (uint_)f2b(a[4]) | ((uint_)f2b(a[5]) << 16);
            o.w = (uint_)f2b(a[6]) | ((uint_)f2b(a[7]) << 16);
            *(uint4*)(Zs + nn * 168 + 24 + l8 * 8) = o;   // kk 24..87
        }
    }

    f32x4 acc[4][NT];
#pragma unroll
    for (int mt = 0; mt < 4; mt++)
#pragma unroll
        for (int nt = 0; nt < NT; nt++) acc[mt][nt] = (f32x4)(0.f);

    for (int kt = 0; kt < 5; ++kt) {
        __syncthreads();   // first iter: also covers Zs completion
#pragma unroll
        for (int i = 0; i < JW / 64; ++i) {
            int slot = tid + 256 * i;
            int n = slot >> 2, oct = slot & 3;
            uint4 v = *(const uint4*)(WgB + (size_t)n * KF + kt * 32 + oct * 8);
            *(uint4*)(Ws + n * 40 + oct * 8) = v;
        }
        __syncthreads();
        bf16x8 af[4], bf[NT];
#pragma unroll
        for (int mt = 0; mt < 4; mt++)
            af[mt] = *(const bf16x8*)(Zs + (mt * 16 + l16) * 168 + kt * 32 + q * 8);
#pragma unroll
        for (int nt = 0; nt < NT; nt++) {
            int n = (nt < 4) ? (w * 64 + nt * 16 + l16) : (256 + w * 16 + l16);
            bf[nt] = *(const bf16x8*)(Ws + n * 40 + q * 8);
        }
#pragma unroll
        for (int mt = 0; mt < 4; mt++)
#pragma unroll
            for (int nt = 0; nt < NT; nt++)
                acc[mt][nt] = __builtin_amdgcn_mfma_f32_16x16x32_bf16(af[mt], bf[nt], acc[mt][nt], 0, 0, 0);
    }

    // ---- epilogue: thread holds i,f,g,o (nt 0..3) for j = w*16+l16, nodes mt*16+q*4+r ----
    const int j = w * 16 + l16;
    const f32x4 bias = *(const f32x4*)(bgp + j * 4);
    const float brl = LAST ? bgp[256 + j] : 0.f;
    float sh = 0.f, sh2 = 0.f, sg = 0.f, sg2 = 0.f;
#pragma unroll
    for (int mt = 0; mt < 4; ++mt) {
#pragma unroll
        for (int r = 0; r < 4; ++r) {
            int node = nblk + mt * 16 + q * 4 + r;
            if (node >= NN) continue;
            size_t idx = (size_t)node * 64 + j;
            float iv = sigf(acc[mt][0][r] + bias.x);
            float fv = sigf(acc[mt][1][r] + bias.y);
            float gv = tanhf_(acc[mt][2][r] + bias.z);
            float ov = sigf(acc[mt][3][r] + bias.w);
            float cn = fv * c[idx] + iv * gv;
            float hn = ov * tanhf_(cn);
            c[idx] = cn;
            hbW[idx] = f2b(hn);
            if (LAST) {
                float gn = acc[mt][4][r] + brl;
                hf[idx] = hn;
                gnn[idx] = gn;
                sh += hn; sh2 += hn * hn;
                sg += gn; sg2 += gn * gn;
            }
        }
    }
    if (LAST) {
        // reduce across q (lanes l16, 16+l16, 32+l16, 48+l16 share j)
#pragma unroll
        for (int d = 16; d < 64; d <<= 1) {
            sh += __shfl_xor(sh, d, 64);
            sh2 += __shfl_xor(sh2, d, 64);
            sg += __shfl_xor(sg, d, 64);
            sg2 += __shfl_xor(sg2, d, 64);
        }
        if (q == 0) {
            atomicAdd(&sums[j], sh);
            atomicAdd(&sumsq[j], sh2);
            atomicAdd(&sums[64 + j], sg);
            atomicAdd(&sumsq[64 + j], sg2);
        }
    }
}

// ---------------- head: BN-apply + relu(W1) + relu(W2) + sigmoid(W_out), all fused ----------------
__global__ __launch_bounds__(256) void k_head(const float* __restrict__ hf,
                                              const float* __restrict__ gnn,
                                              const float* __restrict__ sums,
                                              const float* __restrict__ sumsq,
                                              const float* __restrict__ gamma,
                                              const float* __restrict__ beta,
                                              const float* __restrict__ W1,
                                              const float* __restrict__ b1,
                                              const float* __restrict__ W2,
                                              const float* __restrict__ b2,
                                              const float* __restrict__ W_out,
                                              const float* __restrict__ b_out,
                                              float* __restrict__ out) {
    __shared__ float W1T[128 * 66];
    __shared__ float W2T[64 * 130];
    __shared__ float ab[256];
    __shared__ float fr[4][128];
    __shared__ float h1s[4][64];
    int tid = threadIdx.x, w = tid >> 6, lane = tid & 63;
    if (tid < 128) {
        float mean = sums[tid] / (float)NN;
        float var = sumsq[tid] / (float)NN - mean * mean;
        float a = gamma[tid] * rsqrtf(var + 1e-5f);
        ab[tid] = a;
        ab[128 + tid] = beta[tid] - mean * a;
    }
    for (int idx = tid; idx < 64 * 128; idx += 256) {
        int jj = idx >> 7, k = idx & 127;
        W1T[k * 66 + jj] = W1[idx];
    }
    for (int idx = tid; idx < 128 * 64; idx += 256) {
        int jj = idx >> 6, k = idx & 63;
        W2T[k * 130 + jj] = W2[idx];
    }
    __syncthreads();
    float bb1 = b1[lane];
    float wo0 = W_out[lane], wo1 = W_out[64 + lane];
    float bb20 = b2[lane], bb21 = b2[64 + lane], bo = b_out[0];
    for (int n = blockIdx.x * 4 + w; n < NN; n += gridDim.x * 4) {
        float v0 = hf[(size_t)n * 64 + lane] * ab[lane] + ab[128 + lane];
        float v1 = gnn[(size_t)n * 64 + lane] * ab[64 + lane] + ab[192 + lane];
        fr[w][lane] = v0;
        fr[w][64 + lane] = v1;
        __threadfence_block();
        float a = bb1;
#pragma unroll 8
        for (int k = 0; k < 128; k++) a += fr[w][k] * W1T[k * 66 + lane];
        h1s[w][lane] = fmaxf(a, 0.f);
        __threadfence_block();
        float a0 = bb20, a1 = bb21;
#pragma unroll 8
        for (int k = 0; k < 64; k++) {
            float hv = h1s[w][k];
            a0 += hv * W2T[k * 130 + lane];
            a1 += hv * W2T[k * 130 + 64 + lane];
        }
        float p = fmaxf(a0, 0.f) * wo0 + fmaxf(a1, 0.f) * wo1;
        for (int o2 = 32; o2; o2 >>= 1) p += __shfl_down(p, o2, 64);
        if (lane == 0) out[n] = sigf(p + bo);
        __threadfence_block();
    }
}

extern "C" void kernel_launch(void* const* d_in, const int* in_sizes, int n_in,
                              void* d_out, int out_size, void* d_ws, size_t ws_size,
                              hipStream_t stream) {
    const float* x      = (const float*)d_in[0];
    const int*   ei     = (const int*)d_in[1];
    const float* W_ih   = (const float*)d_in[4];
    const float* W_hh   = (const float*)d_in[5];
    const float* b_ih   = (const float*)d_in[6];
    const float* b_hh   = (const float*)d_in[7];
    const float* W_rel  = (const float*)d_in[8];
    const float* b_rel  = (const float*)d_in[9];
    const float* W_root = (const float*)d_in[10];
    const float* gamma  = (const float*)d_in[11];
    const float* beta   = (const float*)d_in[12];
    const float* W1     = (const float*)d_in[13];
    const float* b1     = (const float*)d_in[14];
    const float* W2     = (const float*)d_in[15];
    const float* b2     = (const float*)d_in[16];
    const float* W_out  = (const float*)d_in[17];
    const float* b_out  = (const float*)d_in[18];
    float* out = (float*)d_out;

    char* ws = (char*)d_ws;
    size_t o = 0;
    auto carve = [&](size_t bytes) { char* p = ws + o; o += (bytes + 255) & ~(size_t)255; return p; };
    int*     off   = (int*)carve((NN + 1) * 4);
    int*     cnt   = (int*)carve(NN * 4);          // reused as cursor
    int*     bsum  = (int*)carve(128 * 4);
    int*     flag  = (int*)carve(256);
    int*     csr   = (int*)carve((size_t)NE * 4);
    float*   hf    = (float*)carve((size_t)NN * 64 * 4);   // fp32 h (written at t=7 only)
    float*   c     = (float*)carve((size_t)NN * 64 * 4);
    float*   gnn   = (float*)carve((size_t)NN * 64 * 4);
    ushort_* hbA   = (ushort_*)carve((size_t)NN * 64 * 2); // bf16 h ping
    ushort_* hbB   = (ushort_*)carve((size_t)NN * 64 * 2); // bf16 h pong
    ushort_* WgB   = (ushort_*)carve((size_t)320 * KF * 2);
    float*   bgp   = (float*)carve(320 * 4);
    float*   sums  = (float*)carve(128 * 4);
    float*   sumsq = (float*)carve(128 * 4);
    // optional bf16 x-transpose (guarded on ws_size)
    ushort_* xT = nullptr;
    size_t need_xt = (size_t)TT * NN * XSTR * 2;
    if (o + need_xt + 256 <= ws_size) xT = (ushort_*)carve(need_xt);

    const int nscan = (NN + 1023) / 1024;   // 98
    const int xtb = xT ? (NN * XSTR + 255) / 256 : 0;

    // edge dtype detect + CSR build (+ x transpose overlapped with hist)
    hipMemsetAsync(flag, 0, 4, stream);
    hipMemsetAsync(cnt, 0, NN * 4, stream);
    k_detect<<<16, 256, 0, stream>>>(ei, flag);
    k_hist_xt<<<HISTB + xtb, 256, 0, stream>>>(ei, flag, cnt, x, xT);
    k_scanblk<<<nscan, 1024, 0, stream>>>(cnt, off, bsum);
    k_scantop<<<1, 64, 0, stream>>>(bsum, nscan);
    k_scanadd<<<nscan, 1024, 0, stream>>>(off, bsum);
    hipMemcpyAsync(cnt, off, NN * 4, hipMemcpyDeviceToDevice, stream);  // cursor = off
    k_scatter<<<(NE + 255) / 256, 256, 0, stream>>>(ei, flag, cnt, csr);

    // init state + folded weights + BN accumulators
    hipMemsetAsync(c, 0, (size_t)NN * 64 * 4, stream);
    hipMemsetAsync(hbA, 0, (size_t)NN * 64 * 2, stream);   // t=0 reads hbA
    hipMemsetAsync(sums, 0, 1024, stream);                 // sums + sumsq (contiguous carves)
    k_prep<<<KF + 1, 320, 0, stream>>>(W_ih, W_hh, b_ih, b_hh, W_rel, b_rel, W_root, WgB, bgp);

    // 8 fused steps (ping-pong bf16 h)
    const int ngates = (NN + 63) / 64;
    for (int t = 0; t < TT; ++t) {
        ushort_* hbR = (t & 1) ? hbB : hbA;
        ushort_* hbW = (t & 1) ? hbA : hbB;
        if (t == TT - 1)
            k_step<true><<<ngates, 256, 0, stream>>>(x, xT, off, csr, hbR, hbW, hf, c,
                                                     WgB, bgp, gnn, sums, sumsq, t);
        else
            k_step<false><<<ngates, 256, 0, stream>>>(x, xT, off, csr, hbR, hbW, hf, c,
                                                      WgB, bgp, nullptr, nullptr, nullptr, t);
    }

    // fused BN + MLP head
    k_head<<<1024, 256, 0, stream>>>(hf, gnn, sums, sumsq, gamma, beta,
                                     W1, b1, W2, b2, W_out, b_out, out);
}

// Round 5
// 1149.288 us; speedup vs baseline: 2.4034x; 1.0480x over previous
//
#include <hip/hip_runtime.h>

#define NN 100000
#define NE 1600000
#define TT 8
#define KF 160        // padded K: x 0..19 | pad 20..23 | agg 24..87 | h 88..151 | pad 152..159
#define XSTR 24       // xT row stride (20 + 4 zero pad), bf16
#define HISTB 6250    // hist blocks in the merged hist+xt kernel
#define NRANGE 8      // scatter dst ranges (XCD-pinned via blockIdx&7)
#define RSPAN 12500   // NN / NRANGE

typedef __attribute__((ext_vector_type(8))) short bf16x8;
typedef __attribute__((ext_vector_type(4))) float f32x4;
typedef unsigned int uint_;
typedef unsigned short ushort_;

__device__ __forceinline__ float sigf(float x) { return 1.f / (1.f + __expf(-x)); }
__device__ __forceinline__ float tanhf_(float x) { return 1.f - 2.f / (__expf(2.f * x) + 1.f); }
__device__ __forceinline__ ushort_ f2b(float f) {
    uint_ u = __float_as_uint(f);
    u += 0x7fff + ((u >> 16) & 1);
    return (ushort_)(u >> 16);
}
__device__ __forceinline__ float bl(uint_ u) { return __uint_as_float(u << 16); }
__device__ __forceinline__ float bh(uint_ u) { return __uint_as_float(u & 0xffff0000u); }
__device__ __forceinline__ void acc8(float* a, uint4 v) {
    a[0] += bl(v.x); a[1] += bh(v.x); a[2] += bl(v.y); a[3] += bh(v.y);
    a[4] += bl(v.z); a[5] += bh(v.z); a[6] += bl(v.w); a[7] += bh(v.w);
}
__device__ __forceinline__ uint_ pk(float a, float b) {
    return (uint_)f2b(a) | ((uint_)f2b(b) << 16);
}

// ---------------- edge dtype detect: int64 => odd int32 words are all 0 ----------------
__global__ void k_detect(const int* __restrict__ ei, int* flag) {
    int i = blockIdx.x * 256 + threadIdx.x;
    if (ei[2 * i + 1] != 0) atomicOr(flag, 1);
}

// ---------------- merged: dst histogram + x transpose (independent work, overlapped) ----------------
__global__ void k_hist_xt(const int* __restrict__ ei, const int* __restrict__ flag, int* cnt,
                          const float* __restrict__ x, ushort_* __restrict__ xT) {
    int b = blockIdx.x;
    if (b < HISTB) {
        int e = b * 256 + threadIdx.x;
        if (e >= NE) return;
        int is32 = *flag;
        int d = is32 ? ei[NE + e] : ei[2 * (NE + e)];
        atomicAdd(&cnt[d], 1);
    } else {
        if (!xT) return;
        int i = (b - HISTB) * 256 + threadIdx.x;   // n*24 + kk
        if (i >= NN * XSTR) return;
        int n = i / XSTR, kk = i - n * XSTR;
        if (kk < 20) {
            const float* xp = x + (size_t)n * 240 + (10 + kk) * 8;
#pragma unroll
            for (int t = 0; t < 8; t++) xT[(size_t)t * NN * XSTR + i] = f2b(xp[t]);
        } else {
#pragma unroll
            for (int t = 0; t < 8; t++) xT[(size_t)t * NN * XSTR + i] = 0;
        }
    }
}

// ---------------- CSR scan ----------------
__global__ void k_scanblk(const int* __restrict__ cnt, int* off, int* bsum) {
    __shared__ int tmp[1024];
    int i = blockIdx.x * 1024 + threadIdx.x;
    int v = (i < NN) ? cnt[i] : 0;
    tmp[threadIdx.x] = v;
    __syncthreads();
    for (int d = 1; d < 1024; d <<= 1) {
        int t = (threadIdx.x >= d) ? tmp[threadIdx.x - d] : 0;
        __syncthreads();
        tmp[threadIdx.x] += t;
        __syncthreads();
    }
    if (i < NN) off[i + 1] = tmp[threadIdx.x];
    if (threadIdx.x == 1023) bsum[blockIdx.x] = tmp[1023];
}

__global__ void k_scantop(int* bsum, int nb) {
    if (threadIdx.x == 0) {
        int run = 0;
        for (int b = 0; b < nb; b++) { int t = bsum[b]; bsum[b] = run; run += t; }
    }
}

__global__ void k_scanadd(int* off, const int* __restrict__ bsum) {
    int i = blockIdx.x * 1024 + threadIdx.x;
    if (i < NN) off[i + 1] += bsum[blockIdx.x];
    if (i == 0) off[0] = 0;
}

// ---------------- scatter, dst-range partitioned (range pinned to XCD via blockIdx&7) ----------------
// 8x streaming re-read of dst, but cursor (50KB) + csr window (800KB) per range dwell in one XCD L2.
__global__ void k_scatter(const int* __restrict__ ei, const int* __restrict__ flag,
                          int* cursor, int* csr) {
    int b = blockIdx.x;
    int range = b & (NRANGE - 1), chunk = b >> 3;
    int e = chunk * 256 + threadIdx.x;
    if (e >= NE) return;
    int is32 = *flag;
    int d = is32 ? ei[NE + e] : ei[2 * (NE + e)];
    if (d / RSPAN != range) return;
    int s = is32 ? ei[e] : ei[2 * e];
    int pos = atomicAdd(&cursor[d], 1);
    csr[pos] = s;
}

// ---------------- fold weights into WgB bf16 [n=320][KF], gate-interleaved cols ----------------
__global__ void k_prep(const float* __restrict__ W_ih, const float* __restrict__ W_hh,
                       const float* __restrict__ b_ih, const float* __restrict__ b_hh,
                       const float* __restrict__ W_rel, const float* __restrict__ b_rel,
                       const float* __restrict__ W_root, ushort_* WgB, float* bgp) {
    int n = threadIdx.x;          // 0..319
    int k = blockIdx.x;           // 0..159 rows; 160 => bias
    if (k < KF) {
        float v = 0.f;
        if (n < 256) {
            int w = n >> 6, g = (n >> 4) & 3, j = w * 16 + (n & 15);
            int row = g * 64 + j;
            if (k < 20) {
                v = W_ih[row * 84 + k];
            } else if (k >= 24 && k < 88) {
                int kk = k - 24;
                float a = 0.f;
                for (int m = 0; m < 64; m++) a += W_ih[row * 84 + 20 + m] * W_rel[m * 64 + kk];
                v = a;
            } else if (k >= 88 && k < 152) {
                int kk = k - 88;
                float a = W_hh[row * 64 + kk];
                for (int m = 0; m < 64; m++) a += W_ih[row * 84 + 20 + m] * W_root[m * 64 + kk];
                v = a;
            }
        } else {
            int j = n - 256;
            if (k >= 24 && k < 88) v = W_rel[j * 64 + (k - 24)];
            else if (k >= 88 && k < 152) v = W_root[j * 64 + (k - 88)];
        }
        WgB[(size_t)n * KF + k] = f2b(v);
    } else {
        if (n < 256) {
            int j = n >> 2, g = n & 3;            // bgp[j*4+g]
            int row = g * 64 + j;
            float a = b_ih[row] + b_hh[row];
            for (int m = 0; m < 64; m++) a += W_ih[row * 84 + 20 + m] * b_rel[m];
            bgp[n] = a;
        } else {
            bgp[n] = b_rel[n - 256];
        }
    }
}

// ---------------- fused step: gather (CSR segment sum) + MFMA gates + LSTM cell ----------------
template <bool LAST>
__global__ __launch_bounds__(256) void k_step(const float* __restrict__ x,
                                              const ushort_* __restrict__ xT,
                                              const int* __restrict__ off,
                                              const int* __restrict__ csr,
                                              const ushort_* __restrict__ hbR,
                                              ushort_* __restrict__ hbW,
                                              float* __restrict__ hf,
                                              float* __restrict__ c,
                                              const ushort_* __restrict__ WgB,
                                              const float* __restrict__ bgp,
                                              float* __restrict__ gnn,
                                              float* __restrict__ sums,
                                              float* __restrict__ sumsq, int t) {
    constexpr int JW = LAST ? 320 : 256;
    constexpr int NT = LAST ? 5 : 4;
    __shared__ __align__(16) ushort_ Zs[64 * 168];   // [node][KF pad 168]
    __shared__ __align__(16) ushort_ Ws[JW * 40];    // per-kt [n][32 pad 40]
    const int tid = threadIdx.x;
    const int nblk = blockIdx.x * 64;
    const int w = tid >> 6, lane = tid & 63;
    const int q = lane >> 4, l16 = lane & 15;

    // ---- stage x (octs 0..2), h (octs 11..18), zero-pad (oct 19): 64 nodes x 12 slots ----
#pragma unroll
    for (int i = 0; i < 3; ++i) {
        int slot = tid + 256 * i;
        int n = slot / 12, oo = slot - n * 12;
        int n_g = nblk + n;
        uint4 z = make_uint4(0, 0, 0, 0);
        if (n_g < NN) {
            if (oo < 3) {
                if (xT) {
                    z = *(const uint4*)(xT + ((size_t)t * NN + n_g) * XSTR + oo * 8);
                } else {
                    const float* xp = x + (size_t)n_g * 240 + 80 + (size_t)oo * 64 + t;
                    uint_ r[4];
#pragma unroll
                    for (int p = 0; p < 4; p++) {
                        int k0 = oo * 8 + p * 2;
                        ushort_ b0 = (k0 < 20) ? f2b(xp[p * 16]) : (ushort_)0;
                        ushort_ b1 = (k0 + 1 < 20) ? f2b(xp[p * 16 + 8]) : (ushort_)0;
                        r[p] = (uint_)b0 | ((uint_)b1 << 16);
                    }
                    z = make_uint4(r[0], r[1], r[2], r[3]);
                }
            } else if (oo < 11) {
                z = *(const uint4*)(hbR + (size_t)n_g * 64 + (oo - 3) * 8);
            }
        }
        int oct = (oo < 3) ? oo : ((oo < 11) ? (oo + 8) : 19);
        *(uint4*)(Zs + n * 168 + oct * 8) = z;
    }

    // ---- gather phase: 8-lane group per node, lane l8 owns features l8*8..+7, fp32 accum ----
    {
        int slot = tid >> 3;       // 0..31
        int l8 = tid & 7;
        for (int nn = slot; nn < 64; nn += 32) {
            int node = nblk + nn;
            float a[8];
#pragma unroll
            for (int i = 0; i < 8; i++) a[i] = 0.f;
            if (t > 0 && node < NN) {
                int e0 = off[node], e1 = off[node + 1];
                int e = e0;
                for (; e + 8 <= e1; e += 8) {
                    uint4 v0 = *(const uint4*)(hbR + (size_t)csr[e] * 64 + l8 * 8);
                    uint4 v1 = *(const uint4*)(hbR + (size_t)csr[e + 1] * 64 + l8 * 8);
                    uint4 v2 = *(const uint4*)(hbR + (size_t)csr[e + 2] * 64 + l8 * 8);
                    uint4 v3 = *(const uint4*)(hbR + (size_t)csr[e + 3] * 64 + l8 * 8);
                    uint4 v4 = *(const uint4*)(hbR + (size_t)csr[e + 4] * 64 + l8 * 8);
                    uint4 v5 = *(const uint4*)(hbR + (size_t)csr[e + 5] * 64 + l8 * 8);
                    uint4 v6 = *(const uint4*)(hbR + (size_t)csr[e + 6] * 64 + l8 * 8);
                    uint4 v7 = *(const uint4*)(hbR + (size_t)csr[e + 7] * 64 + l8 * 8);
                    acc8(a, v0); acc8(a, v1); acc8(a, v2); acc8(a, v3);
                    acc8(a, v4); acc8(a, v5); acc8(a, v6); acc8(a, v7);
                }
                for (; e < e1; e++) {
                    uint4 v0 = *(const uint4*)(hbR + (size_t)csr[e] * 64 + l8 * 8);
                    acc8(a, v0);
                }
            }
            uint4 o;
            o.x = pk(a[0], a[1]); o.y = pk(a[2], a[3]);
            o.z = pk(a[4], a[5]); o.w = pk(a[6], a[7]);
            *(uint4*)(Zs + nn * 168 + 24 + l8 * 8) = o;   // kk 24..87
        }
    }

    f32x4 acc[4][NT];
#pragma unroll
    for (int mt = 0; mt < 4; mt++)
#pragma unroll
        for (int nt = 0; nt < NT; nt++) acc[mt][nt] = (f32x4)(0.f);

    for (int kt = 0; kt < 5; ++kt) {
        __syncthreads();   // first iter: also covers Zs completion
#pragma unroll
        for (int i = 0; i < JW / 64; ++i) {
            int slot = tid + 256 * i;
            int n = slot >> 2, oct = slot & 3;
            uint4 v = *(const uint4*)(WgB + (size_t)n * KF + kt * 32 + oct * 8);
            *(uint4*)(Ws + n * 40 + oct * 8) = v;
        }
        __syncthreads();
        bf16x8 af[4], bf[NT];
#pragma unroll
        for (int mt = 0; mt < 4; mt++)
            af[mt] = *(const bf16x8*)(Zs + (mt * 16 + l16) * 168 + kt * 32 + q * 8);
#pragma unroll
        for (int nt = 0; nt < NT; nt++) {
            int n = (nt < 4) ? (w * 64 + nt * 16 + l16) : (256 + w * 16 + l16);
            bf[nt] = *(const bf16x8*)(Ws + n * 40 + q * 8);
        }
#pragma unroll
        for (int mt = 0; mt < 4; mt++)
#pragma unroll
            for (int nt = 0; nt < NT; nt++)
                acc[mt][nt] = __builtin_amdgcn_mfma_f32_16x16x32_bf16(af[mt], bf[nt], acc[mt][nt], 0, 0, 0);
    }

    // ---- epilogue ----
    const int j = w * 16 + l16;
    const f32x4 bias = *(const f32x4*)(bgp + j * 4);
    const float brl = LAST ? bgp[256 + j] : 0.f;
    float sh = 0.f, sh2 = 0.f, sg = 0.f, sg2 = 0.f;
#pragma unroll
    for (int mt = 0; mt < 4; ++mt) {
#pragma unroll
        for (int r = 0; r < 4; ++r) {
            int node = nblk + mt * 16 + q * 4 + r;
            if (node >= NN) continue;
            size_t idx = (size_t)node * 64 + j;
            float iv = sigf(acc[mt][0][r] + bias.x);
            float fv = sigf(acc[mt][1][r] + bias.y);
            float gv = tanhf_(acc[mt][2][r] + bias.z);
            float ov = sigf(acc[mt][3][r] + bias.w);
            float cn = fv * c[idx] + iv * gv;
            float hn = ov * tanhf_(cn);
            c[idx] = cn;
            hbW[idx] = f2b(hn);
            if (LAST) {
                float gn = acc[mt][4][r] + brl;
                hf[idx] = hn;
                gnn[idx] = gn;
                sh += hn; sh2 += hn * hn;
                sg += gn; sg2 += gn * gn;
            }
        }
    }
    if (LAST) {
#pragma unroll
        for (int d = 16; d < 64; d <<= 1) {
            sh += __shfl_xor(sh, d, 64);
            sh2 += __shfl_xor(sh2, d, 64);
            sg += __shfl_xor(sg, d, 64);
            sg2 += __shfl_xor(sg2, d, 64);
        }
        if (q == 0) {
            atomicAdd(&sums[j], sh);
            atomicAdd(&sumsq[j], sh2);
            atomicAdd(&sums[64 + j], sg);
            atomicAdd(&sumsq[64 + j], sg2);
        }
    }
}

// ---------------- MFMA head: BN-apply + relu(W1) + relu(W2) + sigmoid(W_out) ----------------
// per 64-node tile: Zs = normed bf16 (64x128) -> MFMA W1 -> H1s bf16 (64x64) -> MFMA W2
// -> relu * W_out dot (shuffle + LDS reduce) -> out
__global__ __launch_bounds__(256) void k_head(const float* __restrict__ hf,
                                              const float* __restrict__ gnn,
                                              const float* __restrict__ sums,
                                              const float* __restrict__ sumsq,
                                              const float* __restrict__ gamma,
                                              const float* __restrict__ beta,
                                              const float* __restrict__ W1,
                                              const float* __restrict__ b1,
                                              const float* __restrict__ W2,
                                              const float* __restrict__ b2,
                                              const float* __restrict__ W_out,
                                              const float* __restrict__ b_out,
                                              float* __restrict__ out) {
    __shared__ __align__(16) ushort_ Zs[64 * 168];    // normed [node][F pad]
    __shared__ __align__(16) ushort_ W1s[64 * 168];   // W1 rows [j][k=128 pad]
    __shared__ __align__(16) ushort_ W2s[128 * 72];   // W2 rows [j2][k=64 pad]
    __shared__ __align__(16) ushort_ H1s[64 * 72];    // h1 bf16 [node][j pad]
    __shared__ float ab[256];
    __shared__ float Obuf[4][64];
    const int tid = threadIdx.x;
    const int w = tid >> 6, lane = tid & 63;
    const int q = lane >> 4, l16 = lane & 15;

    if (tid < 128) {
        float mean = sums[tid] / (float)NN;
        float var = sumsq[tid] / (float)NN - mean * mean;
        float a = gamma[tid] * rsqrtf(var + 1e-5f);
        ab[tid] = a;
        ab[128 + tid] = beta[tid] - mean * a;
    }
    // stage W1 (64x128) and W2 (128x64) as bf16, once per block
#pragma unroll
    for (int i = 0; i < 8; ++i) {
        int slot = tid + 256 * i;
        int jj = slot >> 5, k4 = slot & 31;
        float4 v = *(const float4*)(W1 + (size_t)jj * 128 + k4 * 4);
        *(uint2*)(W1s + jj * 168 + k4 * 4) = make_uint2(pk(v.x, v.y), pk(v.z, v.w));
    }
#pragma unroll
    for (int i = 0; i < 8; ++i) {
        int slot = tid + 256 * i;
        int jj = slot >> 4, k4 = slot & 15;
        float4 v = *(const float4*)(W2 + (size_t)jj * 64 + k4 * 4);
        *(uint2*)(W2s + jj * 72 + k4 * 4) = make_uint2(pk(v.x, v.y), pk(v.z, v.w));
    }
    const int j1 = w * 16 + l16;
    const float bb1 = b1[j1];
    const int j2a = (w * 2) * 16 + l16, j2b = (w * 2 + 1) * 16 + l16;
    const float bb2a = b2[j2a], bb2b = b2[j2b];
    const float woa = W_out[j2a], wob = W_out[j2b];
    const float bo = b_out[0];
    __syncthreads();

    const int NTILE = (NN + 63) / 64;
    for (int tile = blockIdx.x; tile < NTILE; tile += gridDim.x) {
        const int nblk = tile * 64;
        // ---- stage normed Z (64 nodes x 128 feats) ----
#pragma unroll
        for (int i = 0; i < 8; ++i) {
            int slot = tid + 256 * i;
            int n = slot >> 5, f4 = slot & 31;
            int n_g = nblk + n;
            uint2 z = make_uint2(0, 0);
            if (n_g < NN) {
                const float* src = (f4 < 16) ? (hf + (size_t)n_g * 64 + f4 * 4)
                                             : (gnn + (size_t)n_g * 64 + (f4 - 16) * 4);
                float4 v = *(const float4*)src;
                int F = f4 * 4;
                z = make_uint2(pk(v.x * ab[F] + ab[128 + F], v.y * ab[F + 1] + ab[129 + F]),
                               pk(v.z * ab[F + 2] + ab[130 + F], v.w * ab[F + 3] + ab[131 + F]));
            }
            *(uint2*)(Zs + n * 168 + f4 * 4) = z;
        }
        __syncthreads();
        // ---- GEMM1: h1[64 x 64], wave w owns j-tile w ----
        f32x4 acc1[4];
#pragma unroll
        for (int mt = 0; mt < 4; mt++) acc1[mt] = (f32x4)(0.f);
#pragma unroll
        for (int kt = 0; kt < 4; ++kt) {
            bf16x8 bfw = *(const bf16x8*)(W1s + j1 * 168 + kt * 32 + q * 8);
#pragma unroll
            for (int mt = 0; mt < 4; mt++) {
                bf16x8 af = *(const bf16x8*)(Zs + (mt * 16 + l16) * 168 + kt * 32 + q * 8);
                acc1[mt] = __builtin_amdgcn_mfma_f32_16x16x32_bf16(af, bfw, acc1[mt], 0, 0, 0);
            }
        }
        // relu + bias -> H1s
#pragma unroll
        for (int mt = 0; mt < 4; mt++)
#pragma unroll
            for (int r = 0; r < 4; r++) {
                int nloc = mt * 16 + q * 4 + r;
                H1s[nloc * 72 + j1] = f2b(fmaxf(acc1[mt][r] + bb1, 0.f));
            }
        __syncthreads();
        // ---- GEMM2: hidden[64 x 128], wave w owns j2-tiles {2w, 2w+1} ----
        f32x4 acc2[4][2];
#pragma unroll
        for (int mt = 0; mt < 4; mt++)
#pragma unroll
            for (int nt = 0; nt < 2; nt++) acc2[mt][nt] = (f32x4)(0.f);
#pragma unroll
        for (int kt = 0; kt < 2; ++kt) {
            bf16x8 bfa = *(const bf16x8*)(W2s + j2a * 72 + kt * 32 + q * 8);
            bf16x8 bfb = *(const bf16x8*)(W2s + j2b * 72 + kt * 32 + q * 8);
#pragma unroll
            for (int mt = 0; mt < 4; mt++) {
                bf16x8 af = *(const bf16x8*)(H1s + (mt * 16 + l16) * 72 + kt * 32 + q * 8);
                acc2[mt][0] = __builtin_amdgcn_mfma_f32_16x16x32_bf16(af, bfa, acc2[mt][0], 0, 0, 0);
                acc2[mt][1] = __builtin_amdgcn_mfma_f32_16x16x32_bf16(af, bfb, acc2[mt][1], 0, 0, 0);
            }
        }
        // ---- relu * W_out partial dot, reduce over l16, stash per-wave ----
#pragma unroll
        for (int mt = 0; mt < 4; mt++) {
#pragma unroll
            for (int r = 0; r < 4; r++) {
                float p = fmaxf(acc2[mt][0][r] + bb2a, 0.f) * woa +
                          fmaxf(acc2[mt][1][r] + bb2b, 0.f) * wob;
#pragma unroll
                for (int d = 1; d < 16; d <<= 1) p += __shfl_xor(p, d, 64);
                if (l16 == 0) Obuf[w][mt * 16 + q * 4 + r] = p;
            }
        }
        __syncthreads();
        if (tid < 64) {
            int n_g = nblk + tid;
            if (n_g < NN) {
                float s = Obuf[0][tid] + Obuf[1][tid] + Obuf[2][tid] + Obuf[3][tid];
                out[n_g] = sigf(s + bo);
            }
        }
        __syncthreads();
    }
}

extern "C" void kernel_launch(void* const* d_in, const int* in_sizes, int n_in,
                              void* d_out, int out_size, void* d_ws, size_t ws_size,
                              hipStream_t stream) {
    const float* x      = (const float*)d_in[0];
    const int*   ei     = (const int*)d_in[1];
    const float* W_ih   = (const float*)d_in[4];
    const float* W_hh   = (const float*)d_in[5];
    const float* b_ih   = (const float*)d_in[6];
    const float* b_hh   = (const float*)d_in[7];
    const float* W_rel  = (const float*)d_in[8];
    const float* b_rel  = (const float*)d_in[9];
    const float* W_root = (const float*)d_in[10];
    const float* gamma  = (const float*)d_in[11];
    const float* beta   = (const float*)d_in[12];
    const float* W1     = (const float*)d_in[13];
    const float* b1     = (const float*)d_in[14];
    const float* W2     = (const float*)d_in[15];
    const float* b2     = (const float*)d_in[16];
    const float* W_out  = (const float*)d_in[17];
    const float* b_out  = (const float*)d_in[18];
    float* out = (float*)d_out;

    char* ws = (char*)d_ws;
    size_t o = 0;
    auto carve = [&](size_t bytes) { char* p = ws + o; o += (bytes + 255) & ~(size_t)255; return p; };
    int*     off   = (int*)carve((NN + 1) * 4);
    int*     cnt   = (int*)carve(NN * 4);          // reused as cursor
    int*     bsum  = (int*)carve(128 * 4);
    int*     flag  = (int*)carve(256);
    int*     csr   = (int*)carve((size_t)NE * 4);
    float*   hf    = (float*)carve((size_t)NN * 64 * 4);   // fp32 h (written at t=7 only)
    float*   c     = (float*)carve((size_t)NN * 64 * 4);
    float*   gnn   = (float*)carve((size_t)NN * 64 * 4);
    ushort_* hbA   = (ushort_*)carve((size_t)NN * 64 * 2); // bf16 h ping
    ushort_* hbB   = (ushort_*)carve((size_t)NN * 64 * 2); // bf16 h pong
    ushort_* WgB   = (ushort_*)carve((size_t)320 * KF * 2);
    float*   bgp   = (float*)carve(320 * 4);
    float*   sums  = (float*)carve(128 * 4);
    float*   sumsq = (float*)carve(128 * 4);
    // optional bf16 x-transpose (guarded on ws_size)
    ushort_* xT = nullptr;
    size_t need_xt = (size_t)TT * NN * XSTR * 2;
    if (o + need_xt + 256 <= ws_size) xT = (ushort_*)carve(need_xt);

    const int nscan = (NN + 1023) / 1024;   // 98
    const int xtb = xT ? (NN * XSTR + 255) / 256 : 0;

    // edge dtype detect + CSR build (+ x transpose overlapped with hist)
    hipMemsetAsync(flag, 0, 4, stream);
    hipMemsetAsync(cnt, 0, NN * 4, stream);
    k_detect<<<16, 256, 0, stream>>>(ei, flag);
    k_hist_xt<<<HISTB + xtb, 256, 0, stream>>>(ei, flag, cnt, x, xT);
    k_scanblk<<<nscan, 1024, 0, stream>>>(cnt, off, bsum);
    k_scantop<<<1, 64, 0, stream>>>(bsum, nscan);
    k_scanadd<<<nscan, 1024, 0, stream>>>(off, bsum);
    hipMemcpyAsync(cnt, off, NN * 4, hipMemcpyDeviceToDevice, stream);  // cursor = off
    k_scatter<<<(NE / 256) * NRANGE, 256, 0, stream>>>(ei, flag, cnt, csr);

    // init state + folded weights + BN accumulators
    hipMemsetAsync(c, 0, (size_t)NN * 64 * 4, stream);
    hipMemsetAsync(hbA, 0, (size_t)NN * 64 * 2, stream);   // t=0 reads hbA
    hipMemsetAsync(sums, 0, 1024, stream);                 // sums + sumsq (contiguous carves)
    k_prep<<<KF + 1, 320, 0, stream>>>(W_ih, W_hh, b_ih, b_hh, W_rel, b_rel, W_root, WgB, bgp);

    // 8 fused steps (ping-pong bf16 h)
    const int ngates = (NN + 63) / 64;
    for (int t = 0; t < TT; ++t) {
        ushort_* hbR = (t & 1) ? hbB : hbA;
        ushort_* hbW = (t & 1) ? hbA : hbB;
        if (t == TT - 1)
            k_step<true><<<ngates, 256, 0, stream>>>(x, xT, off, csr, hbR, hbW, hf, c,
                                                     WgB, bgp, gnn, sums, sumsq, t);
        else
            k_step<false><<<ngates, 256, 0, stream>>>(x, xT, off, csr, hbR, hbW, hf, c,
                                                      WgB, bgp, nullptr, nullptr, nullptr, t);
    }

    // fused MFMA head
    k_head<<<512, 256, 0, stream>>>(hf, gnn, sums, sumsq, gamma, beta,
                                    W1, b1, W2, b2, W_out, b_out, out);
}

// Round 6
// 920.749 us; speedup vs baseline: 2.9999x; 1.2482x over previous
//
#include <hip/hip_runtime.h>

#define NN 100000
#define NE 1600000
#define TT 8
#define KF 160        // padded K: x 0..19 | pad 20..23 | agg 24..87 | h 88..151 | pad 152..159
#define XSTR 24       // xT row stride (20 + 4 zero pad), bf16
#define HISTB 6250    // hist blocks in the merged hist+xt kernel
#define NRANGE 8      // scatter dst ranges (XCD-pinned via blockIdx&7)
#define RSPAN 12500   // NN / NRANGE

typedef __attribute__((ext_vector_type(8))) short bf16x8;
typedef __attribute__((ext_vector_type(4))) float f32x4;
typedef unsigned int uint_;
typedef unsigned short ushort_;

__device__ __forceinline__ float sigf(float x) { return 1.f / (1.f + __expf(-x)); }
__device__ __forceinline__ float tanhf_(float x) { return 1.f - 2.f / (__expf(2.f * x) + 1.f); }
__device__ __forceinline__ ushort_ f2b(float f) {
    uint_ u = __float_as_uint(f);
    u += 0x7fff + ((u >> 16) & 1);
    return (ushort_)(u >> 16);
}
__device__ __forceinline__ float bl(uint_ u) { return __uint_as_float(u << 16); }
__device__ __forceinline__ float bh(uint_ u) { return __uint_as_float(u & 0xffff0000u); }
__device__ __forceinline__ void acc8(float* a, uint4 v) {
    a[0] += bl(v.x); a[1] += bh(v.x); a[2] += bl(v.y); a[3] += bh(v.y);
    a[4] += bl(v.z); a[5] += bh(v.z); a[6] += bl(v.w); a[7] += bh(v.w);
}
__device__ __forceinline__ uint_ pk(float a, float b) {
    return (uint_)f2b(a) | ((uint_)f2b(b) << 16);
}

// ---------------- edge dtype detect: int64 => odd int32 words are all 0 ----------------
__global__ void k_detect(const int* __restrict__ ei, int* flag) {
    int i = blockIdx.x * 256 + threadIdx.x;
    if (ei[2 * i + 1] != 0) atomicOr(flag, 1);
}

// ---------------- merged: dst histogram + x transpose (independent work, overlapped) ----------------
__global__ void k_hist_xt(const int* __restrict__ ei, const int* __restrict__ flag, int* cnt,
                          const float* __restrict__ x, ushort_* __restrict__ xT) {
    int b = blockIdx.x;
    if (b < HISTB) {
        int e = b * 256 + threadIdx.x;
        if (e >= NE) return;
        int is32 = *flag;
        int d = is32 ? ei[NE + e] : ei[2 * (NE + e)];
        atomicAdd(&cnt[d], 1);
    } else {
        if (!xT) return;
        int i = (b - HISTB) * 256 + threadIdx.x;   // n*24 + kk
        if (i >= NN * XSTR) return;
        int n = i / XSTR, kk = i - n * XSTR;
        if (kk < 20) {
            const float* xp = x + (size_t)n * 240 + (10 + kk) * 8;
#pragma unroll
            for (int t = 0; t < 8; t++) xT[(size_t)t * NN * XSTR + i] = f2b(xp[t]);
        } else {
#pragma unroll
            for (int t = 0; t < 8; t++) xT[(size_t)t * NN * XSTR + i] = 0;
        }
    }
}

// ---------------- CSR scan ----------------
__global__ void k_scanblk(const int* __restrict__ cnt, int* off, int* bsum) {
    __shared__ int tmp[1024];
    int i = blockIdx.x * 1024 + threadIdx.x;
    int v = (i < NN) ? cnt[i] : 0;
    tmp[threadIdx.x] = v;
    __syncthreads();
    for (int d = 1; d < 1024; d <<= 1) {
        int t = (threadIdx.x >= d) ? tmp[threadIdx.x - d] : 0;
        __syncthreads();
        tmp[threadIdx.x] += t;
        __syncthreads();
    }
    if (i < NN) off[i + 1] = tmp[threadIdx.x];
    if (threadIdx.x == 1023) bsum[blockIdx.x] = tmp[1023];
}

__global__ void k_scantop(int* bsum, int nb) {
    if (threadIdx.x == 0) {
        int run = 0;
        for (int b = 0; b < nb; b++) { int t = bsum[b]; bsum[b] = run; run += t; }
    }
}

__global__ void k_scanadd(int* off, const int* __restrict__ bsum) {
    int i = blockIdx.x * 1024 + threadIdx.x;
    if (i < NN) off[i + 1] += bsum[blockIdx.x];
    if (i == 0) off[0] = 0;
}

// ---------------- scatter, dst-range partitioned (range pinned to XCD via blockIdx&7) ----------------
__global__ void k_scatter(const int* __restrict__ ei, const int* __restrict__ flag,
                          int* cursor, int* csr) {
    int b = blockIdx.x;
    int range = b & (NRANGE - 1), chunk = b >> 3;
    int e = chunk * 256 + threadIdx.x;
    if (e >= NE) return;
    int is32 = *flag;
    int d = is32 ? ei[NE + e] : ei[2 * (NE + e)];
    if (d / RSPAN != range) return;
    int s = is32 ? ei[e] : ei[2 * e];
    int pos = atomicAdd(&cursor[d], 1);
    csr[pos] = s;
}

// ---------------- fold weights into WgB bf16 [n=320][KF], gate-interleaved cols ----------------
__global__ void k_prep(const float* __restrict__ W_ih, const float* __restrict__ W_hh,
                       const float* __restrict__ b_ih, const float* __restrict__ b_hh,
                       const float* __restrict__ W_rel, const float* __restrict__ b_rel,
                       const float* __restrict__ W_root, ushort_* WgB, float* bgp) {
    int n = threadIdx.x;          // 0..319
    int k = blockIdx.x;           // 0..159 rows; 160 => bias
    if (k < KF) {
        float v = 0.f;
        if (n < 256) {
            int w = n >> 6, g = (n >> 4) & 3, j = w * 16 + (n & 15);
            int row = g * 64 + j;
            if (k < 20) {
                v = W_ih[row * 84 + k];
            } else if (k >= 24 && k < 88) {
                int kk = k - 24;
                float a = 0.f;
                for (int m = 0; m < 64; m++) a += W_ih[row * 84 + 20 + m] * W_rel[m * 64 + kk];
                v = a;
            } else if (k >= 88 && k < 152) {
                int kk = k - 88;
                float a = W_hh[row * 64 + kk];
                for (int m = 0; m < 64; m++) a += W_ih[row * 84 + 20 + m] * W_root[m * 64 + kk];
                v = a;
            }
        } else {
            int j = n - 256;
            if (k >= 24 && k < 88) v = W_rel[j * 64 + (k - 24)];
            else if (k >= 88 && k < 152) v = W_root[j * 64 + (k - 88)];
        }
        WgB[(size_t)n * KF + k] = f2b(v);
    } else {
        if (n < 256) {
            int j = n >> 2, g = n & 3;            // bgp[j*4+g]
            int row = g * 64 + j;
            float a = b_ih[row] + b_hh[row];
            for (int m = 0; m < 64; m++) a += W_ih[row * 84 + 20 + m] * b_rel[m];
            bgp[n] = a;
        } else {
            bgp[n] = b_rel[n - 256];
        }
    }
}

// ---------------- fused step: gather (CSR segment sum) + MFMA gates + LSTM cell ----------------
// LDS = Zs only (22 KB); B-fragments loaded directly from global (WgB is L2-resident).
// One barrier total; __launch_bounds__(256,4) => 4 blocks/CU (16 waves, 50% occupancy).
template <bool LAST>
__global__ __launch_bounds__(256, 4) void k_step(const float* __restrict__ x,
                                                 const ushort_* __restrict__ xT,
                                                 const int* __restrict__ off,
                                                 const int* __restrict__ csr,
                                                 const ushort_* __restrict__ hbR,
                                                 ushort_* __restrict__ hbW,
                                                 float* __restrict__ hf,
                                                 float* __restrict__ c,
                                                 const ushort_* __restrict__ WgB,
                                                 const float* __restrict__ bgp,
                                                 float* __restrict__ gnn,
                                                 float* __restrict__ sums,
                                                 float* __restrict__ sumsq, int t) {
    constexpr int NT = LAST ? 5 : 4;
    __shared__ __align__(16) ushort_ Zs[64 * 168];   // [node][KF pad 168]
    const int tid = threadIdx.x;
    const int nblk = blockIdx.x * 64;
    const int w = tid >> 6, lane = tid & 63;
    const int q = lane >> 4, l16 = lane & 15;

    // ---- stage x (octs 0..2), h (octs 11..18), zero-pad (oct 19): 64 nodes x 12 slots ----
#pragma unroll
    for (int i = 0; i < 3; ++i) {
        int slot = tid + 256 * i;
        int n = slot / 12, oo = slot - n * 12;
        int n_g = nblk + n;
        uint4 z = make_uint4(0, 0, 0, 0);
        if (n_g < NN) {
            if (oo < 3) {
                if (xT) {
                    z = *(const uint4*)(xT + ((size_t)t * NN + n_g) * XSTR + oo * 8);
                } else {
                    const float* xp = x + (size_t)n_g * 240 + 80 + (size_t)oo * 64 + t;
                    uint_ r[4];
#pragma unroll
                    for (int p = 0; p < 4; p++) {
                        int k0 = oo * 8 + p * 2;
                        ushort_ b0 = (k0 < 20) ? f2b(xp[p * 16]) : (ushort_)0;
                        ushort_ b1 = (k0 + 1 < 20) ? f2b(xp[p * 16 + 8]) : (ushort_)0;
                        r[p] = (uint_)b0 | ((uint_)b1 << 16);
                    }
                    z = make_uint4(r[0], r[1], r[2], r[3]);
                }
            } else if (oo < 11) {
                z = *(const uint4*)(hbR + (size_t)n_g * 64 + (oo - 3) * 8);
            }
        }
        int oct = (oo < 3) ? oo : ((oo < 11) ? (oo + 8) : 19);
        *(uint4*)(Zs + n * 168 + oct * 8) = z;
    }

    // ---- gather phase: 8-lane group per node, lane l8 owns features l8*8..+7, fp32 accum ----
    {
        int slot = tid >> 3;       // 0..31
        int l8 = tid & 7;
        for (int nn = slot; nn < 64; nn += 32) {
            int node = nblk + nn;
            float a[8];
#pragma unroll
            for (int i = 0; i < 8; i++) a[i] = 0.f;
            if (t > 0 && node < NN) {
                int e0 = off[node], e1 = off[node + 1];
                int e = e0;
                for (; e + 8 <= e1; e += 8) {
                    uint4 v0 = *(const uint4*)(hbR + (size_t)csr[e] * 64 + l8 * 8);
                    uint4 v1 = *(const uint4*)(hbR + (size_t)csr[e + 1] * 64 + l8 * 8);
                    uint4 v2 = *(const uint4*)(hbR + (size_t)csr[e + 2] * 64 + l8 * 8);
                    uint4 v3 = *(const uint4*)(hbR + (size_t)csr[e + 3] * 64 + l8 * 8);
                    uint4 v4 = *(const uint4*)(hbR + (size_t)csr[e + 4] * 64 + l8 * 8);
                    uint4 v5 = *(const uint4*)(hbR + (size_t)csr[e + 5] * 64 + l8 * 8);
                    uint4 v6 = *(const uint4*)(hbR + (size_t)csr[e + 6] * 64 + l8 * 8);
                    uint4 v7 = *(const uint4*)(hbR + (size_t)csr[e + 7] * 64 + l8 * 8);
                    acc8(a, v0); acc8(a, v1); acc8(a, v2); acc8(a, v3);
                    acc8(a, v4); acc8(a, v5); acc8(a, v6); acc8(a, v7);
                }
                for (; e < e1; e++) {
                    uint4 v0 = *(const uint4*)(hbR + (size_t)csr[e] * 64 + l8 * 8);
                    acc8(a, v0);
                }
            }
            uint4 o;
            o.x = pk(a[0], a[1]); o.y = pk(a[2], a[3]);
            o.z = pk(a[4], a[5]); o.w = pk(a[6], a[7]);
            *(uint4*)(Zs + nn * 168 + 24 + l8 * 8) = o;   // kk 24..87
        }
    }
    __syncthreads();   // Zs complete — only barrier in the kernel

    f32x4 acc[4][NT];
#pragma unroll
    for (int mt = 0; mt < 4; mt++)
#pragma unroll
        for (int nt = 0; nt < NT; nt++) acc[mt][nt] = (f32x4)(0.f);

#pragma unroll
    for (int kt = 0; kt < 5; ++kt) {
        bf16x8 af[4], bf[NT];
#pragma unroll
        for (int mt = 0; mt < 4; mt++)
            af[mt] = *(const bf16x8*)(Zs + (mt * 16 + l16) * 168 + kt * 32 + q * 8);
#pragma unroll
        for (int nt = 0; nt < NT; nt++) {
            int n = (nt < 4) ? (w * 64 + nt * 16 + l16) : (256 + w * 16 + l16);
            bf[nt] = *(const bf16x8*)(WgB + (size_t)n * KF + kt * 32 + q * 8);
        }
#pragma unroll
        for (int mt = 0; mt < 4; mt++)
#pragma unroll
            for (int nt = 0; nt < NT; nt++)
                acc[mt][nt] = __builtin_amdgcn_mfma_f32_16x16x32_bf16(af[mt], bf[nt], acc[mt][nt], 0, 0, 0);
    }

    // ---- epilogue: thread holds i,f,g,o (nt 0..3) for j = w*16+l16, nodes mt*16+q*4+r ----
    const int j = w * 16 + l16;
    const f32x4 bias = *(const f32x4*)(bgp + j * 4);
    const float brl = LAST ? bgp[256 + j] : 0.f;
    float sh = 0.f, sh2 = 0.f, sg = 0.f, sg2 = 0.f;
#pragma unroll
    for (int mt = 0; mt < 4; ++mt) {
#pragma unroll
        for (int r = 0; r < 4; ++r) {
            int node = nblk + mt * 16 + q * 4 + r;
            if (node >= NN) continue;
            size_t idx = (size_t)node * 64 + j;
            float iv = sigf(acc[mt][0][r] + bias.x);
            float fv = sigf(acc[mt][1][r] + bias.y);
            float gv = tanhf_(acc[mt][2][r] + bias.z);
            float ov = sigf(acc[mt][3][r] + bias.w);
            float cn = fv * c[idx] + iv * gv;
            float hn = ov * tanhf_(cn);
            c[idx] = cn;
            hbW[idx] = f2b(hn);
            if (LAST) {
                float gn = acc[mt][4][r] + brl;
                hf[idx] = hn;
                gnn[idx] = gn;
                sh += hn; sh2 += hn * hn;
                sg += gn; sg2 += gn * gn;
            }
        }
    }
    if (LAST) {
#pragma unroll
        for (int d = 16; d < 64; d <<= 1) {
            sh += __shfl_xor(sh, d, 64);
            sh2 += __shfl_xor(sh2, d, 64);
            sg += __shfl_xor(sg, d, 64);
            sg2 += __shfl_xor(sg2, d, 64);
        }
        if (q == 0) {
            atomicAdd(&sums[j], sh);
            atomicAdd(&sumsq[j], sh2);
            atomicAdd(&sums[64 + j], sg);
            atomicAdd(&sumsq[64 + j], sg2);
        }
    }
}

// ---------------- MFMA head: BN-apply + relu(W1) + relu(W2) + sigmoid(W_out) ----------------
__global__ __launch_bounds__(256) void k_head(const float* __restrict__ hf,
                                              const float* __restrict__ gnn,
                                              const float* __restrict__ sums,
                                              const float* __restrict__ sumsq,
                                              const float* __restrict__ gamma,
                                              const float* __restrict__ beta,
                                              const float* __restrict__ W1,
                                              const float* __restrict__ b1,
                                              const float* __restrict__ W2,
                                              const float* __restrict__ b2,
                                              const float* __restrict__ W_out,
                                              const float* __restrict__ b_out,
                                              float* __restrict__ out) {
    __shared__ __align__(16) ushort_ Zs[64 * 168];    // normed [node][F pad]
    __shared__ __align__(16) ushort_ W1s[64 * 168];   // W1 rows [j][k=128 pad]
    __shared__ __align__(16) ushort_ W2s[128 * 72];   // W2 rows [j2][k=64 pad]
    __shared__ __align__(16) ushort_ H1s[64 * 72];    // h1 bf16 [node][j pad]
    __shared__ float ab[256];
    __shared__ float Obuf[4][64];
    const int tid = threadIdx.x;
    const int w = tid >> 6, lane = tid & 63;
    const int q = lane >> 4, l16 = lane & 15;

    if (tid < 128) {
        float mean = sums[tid] / (float)NN;
        float var = sumsq[tid] / (float)NN - mean * mean;
        float a = gamma[tid] * rsqrtf(var + 1e-5f);
        ab[tid] = a;
        ab[128 + tid] = beta[tid] - mean * a;
    }
#pragma unroll
    for (int i = 0; i < 8; ++i) {
        int slot = tid + 256 * i;
        int jj = slot >> 5, k4 = slot & 31;
        float4 v = *(const float4*)(W1 + (size_t)jj * 128 + k4 * 4);
        *(uint2*)(W1s + jj * 168 + k4 * 4) = make_uint2(pk(v.x, v.y), pk(v.z, v.w));
    }
#pragma unroll
    for (int i = 0; i < 8; ++i) {
        int slot = tid + 256 * i;
        int jj = slot >> 4, k4 = slot & 15;
        float4 v = *(const float4*)(W2 + (size_t)jj * 64 + k4 * 4);
        *(uint2*)(W2s + jj * 72 + k4 * 4) = make_uint2(pk(v.x, v.y), pk(v.z, v.w));
    }
    const int j1 = w * 16 + l16;
    const float bb1 = b1[j1];
    const int j2a = (w * 2) * 16 + l16, j2b = (w * 2 + 1) * 16 + l16;
    const float bb2a = b2[j2a], bb2b = b2[j2b];
    const float woa = W_out[j2a], wob = W_out[j2b];
    const float bo = b_out[0];
    __syncthreads();

    const int NTILE = (NN + 63) / 64;
    for (int tile = blockIdx.x; tile < NTILE; tile += gridDim.x) {
        const int nblk = tile * 64;
#pragma unroll
        for (int i = 0; i < 8; ++i) {
            int slot = tid + 256 * i;
            int n = slot >> 5, f4 = slot & 31;
            int n_g = nblk + n;
            uint2 z = make_uint2(0, 0);
            if (n_g < NN) {
                const float* src = (f4 < 16) ? (hf + (size_t)n_g * 64 + f4 * 4)
                                             : (gnn + (size_t)n_g * 64 + (f4 - 16) * 4);
                float4 v = *(const float4*)src;
                int F = f4 * 4;
                z = make_uint2(pk(v.x * ab[F] + ab[128 + F], v.y * ab[F + 1] + ab[129 + F]),
                               pk(v.z * ab[F + 2] + ab[130 + F], v.w * ab[F + 3] + ab[131 + F]));
            }
            *(uint2*)(Zs + n * 168 + f4 * 4) = z;
        }
        __syncthreads();
        f32x4 acc1[4];
#pragma unroll
        for (int mt = 0; mt < 4; mt++) acc1[mt] = (f32x4)(0.f);
#pragma unroll
        for (int kt = 0; kt < 4; ++kt) {
            bf16x8 bfw = *(const bf16x8*)(W1s + j1 * 168 + kt * 32 + q * 8);
#pragma unroll
            for (int mt = 0; mt < 4; mt++) {
                bf16x8 af = *(const bf16x8*)(Zs + (mt * 16 + l16) * 168 + kt * 32 + q * 8);
                acc1[mt] = __builtin_amdgcn_mfma_f32_16x16x32_bf16(af, bfw, acc1[mt], 0, 0, 0);
            }
        }
#pragma unroll
        for (int mt = 0; mt < 4; mt++)
#pragma unroll
            for (int r = 0; r < 4; r++) {
                int nloc = mt * 16 + q * 4 + r;
                H1s[nloc * 72 + j1] = f2b(fmaxf(acc1[mt][r] + bb1, 0.f));
            }
        __syncthreads();
        f32x4 acc2[4][2];
#pragma unroll
        for (int mt = 0; mt < 4; mt++)
#pragma unroll
            for (int nt = 0; nt < 2; nt++) acc2[mt][nt] = (f32x4)(0.f);
#pragma unroll
        for (int kt = 0; kt < 2; ++kt) {
            bf16x8 bfa = *(const bf16x8*)(W2s + j2a * 72 + kt * 32 + q * 8);
            bf16x8 bfb = *(const bf16x8*)(W2s + j2b * 72 + kt * 32 + q * 8);
#pragma unroll
            for (int mt = 0; mt < 4; mt++) {
                bf16x8 af = *(const bf16x8*)(H1s + (mt * 16 + l16) * 72 + kt * 32 + q * 8);
                acc2[mt][0] = __builtin_amdgcn_mfma_f32_16x16x32_bf16(af, bfa, acc2[mt][0], 0, 0, 0);
                acc2[mt][1] = __builtin_amdgcn_mfma_f32_16x16x32_bf16(af, bfb, acc2[mt][1], 0, 0, 0);
            }
        }
#pragma unroll
        for (int mt = 0; mt < 4; mt++) {
#pragma unroll
            for (int r = 0; r < 4; r++) {
                float p = fmaxf(acc2[mt][0][r] + bb2a, 0.f) * woa +
                          fmaxf(acc2[mt][1][r] + bb2b, 0.f) * wob;
#pragma unroll
                for (int d = 1; d < 16; d <<= 1) p += __shfl_xor(p, d, 64);
                if (l16 == 0) Obuf[w][mt * 16 + q * 4 + r] = p;
            }
        }
        __syncthreads();
        if (tid < 64) {
            int n_g = nblk + tid;
            if (n_g < NN) {
                float s = Obuf[0][tid] + Obuf[1][tid] + Obuf[2][tid] + Obuf[3][tid];
                out[n_g] = sigf(s + bo);
            }
        }
        __syncthreads();
    }
}

extern "C" void kernel_launch(void* const* d_in, const int* in_sizes, int n_in,
                              void* d_out, int out_size, void* d_ws, size_t ws_size,
                              hipStream_t stream) {
    const float* x      = (const float*)d_in[0];
    const int*   ei     = (const int*)d_in[1];
    const float* W_ih   = (const float*)d_in[4];
    const float* W_hh   = (const float*)d_in[5];
    const float* b_ih   = (const float*)d_in[6];
    const float* b_hh   = (const float*)d_in[7];
    const float* W_rel  = (const float*)d_in[8];
    const float* b_rel  = (const float*)d_in[9];
    const float* W_root = (const float*)d_in[10];
    const float* gamma  = (const float*)d_in[11];
    const float* beta   = (const float*)d_in[12];
    const float* W1     = (const float*)d_in[13];
    const float* b1     = (const float*)d_in[14];
    const float* W2     = (const float*)d_in[15];
    const float* b2     = (const float*)d_in[16];
    const float* W_out  = (const float*)d_in[17];
    const float* b_out  = (const float*)d_in[18];
    float* out = (float*)d_out;

    char* ws = (char*)d_ws;
    size_t o = 0;
    auto carve = [&](size_t bytes) { char* p = ws + o; o += (bytes + 255) & ~(size_t)255; return p; };
    int*     off   = (int*)carve((NN + 1) * 4);
    int*     cnt   = (int*)carve(NN * 4);          // reused as cursor
    int*     bsum  = (int*)carve(128 * 4);
    int*     flag  = (int*)carve(256);
    int*     csr   = (int*)carve((size_t)NE * 4);
    float*   hf    = (float*)carve((size_t)NN * 64 * 4);   // fp32 h (written at t=7 only)
    float*   c     = (float*)carve((size_t)NN * 64 * 4);
    float*   gnn   = (float*)carve((size_t)NN * 64 * 4);
    ushort_* hbA   = (ushort_*)carve((size_t)NN * 64 * 2); // bf16 h ping
    ushort_* hbB   = (ushort_*)carve((size_t)NN * 64 * 2); // bf16 h pong
    ushort_* WgB   = (ushort_*)carve((size_t)320 * KF * 2);
    float*   bgp   = (float*)carve(320 * 4);
    float*   sums  = (float*)carve(128 * 4);
    float*   sumsq = (float*)carve(128 * 4);
    ushort_* xT = nullptr;
    size_t need_xt = (size_t)TT * NN * XSTR * 2;
    if (o + need_xt + 256 <= ws_size) xT = (ushort_*)carve(need_xt);

    const int nscan = (NN + 1023) / 1024;   // 98
    const int xtb = xT ? (NN * XSTR + 255) / 256 : 0;

    // edge dtype detect + CSR build (+ x transpose overlapped with hist)
    hipMemsetAsync(flag, 0, 4, stream);
    hipMemsetAsync(cnt, 0, NN * 4, stream);
    k_detect<<<16, 256, 0, stream>>>(ei, flag);
    k_hist_xt<<<HISTB + xtb, 256, 0, stream>>>(ei, flag, cnt, x, xT);
    k_scanblk<<<nscan, 1024, 0, stream>>>(cnt, off, bsum);
    k_scantop<<<1, 64, 0, stream>>>(bsum, nscan);
    k_scanadd<<<nscan, 1024, 0, stream>>>(off, bsum);
    hipMemcpyAsync(cnt, off, NN * 4, hipMemcpyDeviceToDevice, stream);  // cursor = off
    k_scatter<<<(NE / 256) * NRANGE, 256, 0, stream>>>(ei, flag, cnt, csr);

    // init state + folded weights + BN accumulators
    hipMemsetAsync(c, 0, (size_t)NN * 64 * 4, stream);
    hipMemsetAsync(hbA, 0, (size_t)NN * 64 * 2, stream);   // t=0 reads hbA
    hipMemsetAsync(sums, 0, 1024, stream);                 // sums + sumsq (contiguous carves)
    k_prep<<<KF + 1, 320, 0, stream>>>(W_ih, W_hh, b_ih, b_hh, W_rel, b_rel, W_root, WgB, bgp);

    // 8 fused steps (ping-pong bf16 h)
    const int ngates = (NN + 63) / 64;
    for (int t = 0; t < TT; ++t) {
        ushort_* hbR = (t & 1) ? hbB : hbA;
        ushort_* hbW = (t & 1) ? hbA : hbB;
        if (t == TT - 1)
            k_step<true><<<ngates, 256, 0, stream>>>(x, xT, off, csr, hbR, hbW, hf, c,
                                                     WgB, bgp, gnn, sums, sumsq, t);
        else
            k_step<false><<<ngates, 256, 0, stream>>>(x, xT, off, csr, hbR, hbW, hf, c,
                                                      WgB, bgp, nullptr, nullptr, nullptr, t);
    }

    // fused MFMA head
    k_head<<<512, 256, 0, stream>>>(hf, gnn, sums, sumsq, gamma, beta,
                                    W1, b1, W2, b2, W_out, b_out, out);
}